// Round 1
// 913.133 us; speedup vs baseline: 1.1859x; 1.1859x over previous
//
#include <hip/hip_runtime.h>
#include <math.h>

#define BB 256
#define LL 20
#define HH 128
#define NH 8
#define D2C 64
#define NTY 4
#define NRL 4
#define CHILDN 30001
#define PARENTN 500
#define N1SN 50000
#define N1DN 20000
#define E1N 300000
#define N2N 20000
#define E2N 200000
#define TT (BB*LL)
#define N4DN 5000
#define E4N 150000
#define EC2PN 8000

typedef __attribute__((ext_vector_type(8))) short bfrag;   // 8 bf16 in 4 VGPRs
typedef __attribute__((ext_vector_type(4))) float ffrag;   // MFMA accumulator

__device__ __forceinline__ unsigned fenc(float f){ unsigned u=__float_as_uint(f); return (u&0x80000000u)? ~u : (u|0x80000000u); }
__device__ __forceinline__ float fdec(unsigned u){ return (u&0x80000000u)? __uint_as_float(u^0x80000000u) : __uint_as_float(~u); }
__device__ __forceinline__ float sigf(float x){ return 1.f/(1.f+expf(-x)); }
__device__ __forceinline__ short f2bf(float f){
  unsigned u = __float_as_uint(f);
  unsigned r = u + 0x7FFFu + ((u>>16)&1u);   // round-to-nearest-even
  return (short)(r>>16);
}

// ---------------- Stage A: feature expansion (tiled: 32 tokens/block) ----------------
__global__ __launch_bounds__(512) void k_featx2(const int* __restrict__ seq, const int* __restrict__ dur,
                        const int* __restrict__ stime, const int* __restrict__ etime,
                        const float* __restrict__ emb, const float* __restrict__ dia_w, const float* __restrict__ dia_b,
                        const float* __restrict__ t2v_w, const float* __restrict__ t2v_b,
                        const float* __restrict__ exp_W, const float* __restrict__ exp_b, float* __restrict__ xout){
  __shared__ float feat[32*273];           // [st(128) | et(128) | tv(16)] per token, stride 273
  int base = blockIdx.x*32;
  int j = threadIdx.x >> 4;                // token 0..31
  int p = threadIdx.x & 15;                // 16 threads/token, 8 cols each
  int row = base + j;
  int node = seq[row];
  float ts = (float)stime[row], te = (float)etime[row];
  const float* ep = emb + (size_t)node*HH;
  float* fr = feat + j*273;
  int o0 = p*8;
  #pragma unroll
  for(int ii=0; ii<8; ii+=4){
    int o = o0 + ii;
    float4 e = *(const float4*)(ep + o);
    float4 st = e, et = e;
    if(o >= D2C){
      float4 w = *(const float4*)(dia_w + (size_t)node*HH + o);
      float4 b = *(const float4*)(dia_b + (size_t)node*HH + o);
      st.x = e.x*sinf(w.x*ts+b.x); st.y = e.y*sinf(w.y*ts+b.y);
      st.z = e.z*sinf(w.z*ts+b.z); st.w = e.w*sinf(w.w*ts+b.w);
      et.x = e.x*sinf(w.x*te+b.x); et.y = e.y*sinf(w.y*te+b.y);
      et.z = e.z*sinf(w.z*te+b.z); et.w = e.w*sinf(w.w*te+b.w);
    }
    fr[o] = st.x; fr[o+1] = st.y; fr[o+2] = st.z; fr[o+3] = st.w;
    fr[128+o] = et.x; fr[128+o+1] = et.y; fr[128+o+2] = et.z; fr[128+o+3] = et.w;
  }
  if(p == 0){
    float td = (float)dur[row];
    #pragma unroll
    for(int i=0;i<16;i++){
      float w = t2v_w[i], b = t2v_b[i];
      fr[256+i] = (i==0) ? (w*td + b) : sinf(w*td + b);
    }
  }
  __syncthreads();
  // GEMM: 32x272 @ 272x128, each thread: 2 rows x 4 cols
  int oc = (threadIdx.x & 31)*4;
  int jg = threadIdx.x >> 5;               // 0..15
  const float* f0 = feat + (jg*2)*273;
  const float* f1 = feat + (jg*2+1)*273;
  float4 a0 = {0,0,0,0}, a1 = {0,0,0,0};
  for(int k=0;k<272;k++){
    float4 w = *(const float4*)(exp_W + (size_t)k*HH + oc);
    float x0 = f0[k], x1 = f1[k];
    a0.x += x0*w.x; a0.y += x0*w.y; a0.z += x0*w.z; a0.w += x0*w.w;
    a1.x += x1*w.x; a1.y += x1*w.y; a1.z += x1*w.z; a1.w += x1*w.w;
  }
  float4 bv = *(const float4*)(exp_b + oc);
  a0.x = fmaxf(a0.x+bv.x, 0.f); a0.y = fmaxf(a0.y+bv.y, 0.f);
  a0.z = fmaxf(a0.z+bv.z, 0.f); a0.w = fmaxf(a0.w+bv.w, 0.f);
  a1.x = fmaxf(a1.x+bv.x, 0.f); a1.y = fmaxf(a1.y+bv.y, 0.f);
  a1.z = fmaxf(a1.z+bv.z, 0.f); a1.w = fmaxf(a1.w+bv.w, 0.f);
  *(float4*)(xout + (size_t)(base + jg*2  )*HH + oc) = a0;
  *(float4*)(xout + (size_t)(base + jg*2+1)*HH + oc) = a1;
}

// tiled x @ Wi + b -> gpre: 16 rows x 512 cols per block; perm=1 reads x in (l*BB+b) layout
__global__ void k_xwi2(const float* x, const float* Wi, const float* bias, float* gpre, int rows, int perm){
  int base = blockIdx.x*16;
  __shared__ float xs[128*17];
  int tid = threadIdx.x;
  #pragma unroll
  for(int s=0;s<8;s++){
    int elem = tid + 256*s;
    int k = elem & 127, j = elem >> 7;
    int r = base + j;
    int src = r;
    if(perm) src = (r % LL)*BB + (r / LL);
    xs[k*17 + j] = (r < rows) ? x[(size_t)src*HH + k] : 0.f;
  }
  __syncthreads();
  int o4 = (tid & 127)*4;
  int ng = tid >> 7;
  float4 a[8];
  #pragma unroll
  for(int j=0;j<8;j++) a[j]=make_float4(0,0,0,0);
  for(int k=0;k<HH;k++){
    float4 w = *(const float4*)(Wi + (size_t)k*512 + o4);
    const float* xr = xs + k*17 + ng*8;
    #pragma unroll
    for(int j=0;j<8;j++){
      float xv = xr[j];
      a[j].x += xv*w.x; a[j].y += xv*w.y; a[j].z += xv*w.z; a[j].w += xv*w.w;
    }
  }
  float4 bv = *(const float4*)(bias + o4);
  #pragma unroll
  for(int j=0;j<8;j++){
    int r = base + ng*8 + j;
    if(r < rows){
      float4 v = a[j];
      v.x += bv.x; v.y += bv.y; v.z += bv.z; v.w += bv.w;
      *(float4*)(gpre + (size_t)r*512 + o4) = v;
    }
  }
}

// fused 20-step LSTM: one block per batch row, Wh column held in registers,
// h/c never leave the CU.  Removes 40 launches + state round-trips.
__global__ __launch_bounds__(512, 2) void k_lstm_fused(const float* __restrict__ gpre,
                                                       const float* __restrict__ Wh,
                                                       float* __restrict__ hout,
                                                       float* __restrict__ hout2){
  int b = blockIdx.x;
  int o = threadIdx.x;
  __shared__ float hs[HH];
  __shared__ float gs[512];
  float wr[HH];
  #pragma unroll
  for(int h=0;h<HH;h++) wr[h] = Wh[(size_t)h*512 + o];
  if(o < HH) hs[o] = 0.f;
  float cc = 0.f;
  const float* gp = gpre + (size_t)b*LL*512 + o;
  __syncthreads();
  for(int l=0;l<LL;l++){
    float gv = gp[(size_t)l*512];
    float a0=0.f,a1=0.f,a2=0.f,a3=0.f;
    #pragma unroll
    for(int h=0;h<HH;h+=4){
      float4 hv = *(const float4*)&hs[h];
      a0 += hv.x*wr[h];   a1 += hv.y*wr[h+1];
      a2 += hv.z*wr[h+2]; a3 += hv.w*wr[h+3];
    }
    gs[o] = gv + ((a0+a1)+(a2+a3));
    __syncthreads();
    if(o < HH){
      float ig = sigf(gs[o]);
      float fg = sigf(gs[HH+o]);
      float gg = tanhf(gs[2*HH+o]);
      float og = sigf(gs[3*HH+o]);
      cc = fg*cc + ig*gg;
      float hh = og*tanhf(cc);
      hs[o] = hh;
      size_t bi = ((size_t)b*LL + l)*HH + o;
      hout[bi] = hh;
      if(hout2) hout2[bi] = hh;
    }
    __syncthreads();
  }
}

__global__ void k_tok(const int* seq, const int* seq_nt, int* tokid, int* toknt){
  int t = blockIdx.x*blockDim.x + threadIdx.x;
  if(t >= TT) return;
  int b = t % BB, l = t / BB;
  tokid[t] = seq[b*LL+l];
  toknt[t] = seq_nt[b*LL+l];
}

// ---------------- conv prep ----------------
__global__ void k_gather_emb(const int* nid, const float* emb, float* dst){
  int i = blockIdx.x; int o = threadIdx.x;
  dst[i*HH+o] = emb[nid[i]*HH+o];
}

__global__ void k_prep2(const int* sel, const float* xg, const int* g1_nid, const int* g1_nt,
                        float* srcbuf, int* gnid2, int* tsrc2){
  int i = blockIdx.x; int o = threadIdx.x;
  int s = sel[i];
  srcbuf[i*HH+o] = xg[s*HH+o];
  if(o==0){ gnid2[i] = g1_nid[s]; tsrc2[i] = g1_nt[s]; }
}

__global__ void k_dst2(const int* tok_sel, const float* xg, const float* h1, float* dst2){
  int t = blockIdx.x; int o = threadIdx.x;
  int b = t % BB, l = t / BB;
  dst2[t*HH+o] = xg[tok_sel[t]*HH+o] + h1[(b*LL+l)*HH+o];
}

__global__ void k_x0(const int* nid, const int* ntype, const float* emb, const float* hist2,
                     const float* skip, float* srcbuf){
  int i = blockIdx.x; int o = threadIdx.x;
  float a = sigf(skip[ntype[i]]);
  int nd = nid[i];
  srcbuf[i*HH+o] = emb[nd*HH+o]*a + hist2[nd*HH+o]*(1.f-a);
}

__global__ void k_zero_intk(int* p, int n){
  int i = blockIdx.x*256 + threadIdx.x;
  if(i < n) p[i] = 0;
}

// block-aggregated type scatter
__global__ void k_scatter_type(const int* types, int n, int* cnts, int* idxb){
  __shared__ int hist[NTY];
  __shared__ int base[NTY];
  int i = blockIdx.x*256 + threadIdx.x;
  if(threadIdx.x < NTY) hist[threadIdx.x] = 0;
  __syncthreads();
  int t = 0, r = 0;
  bool act = (i < n);
  if(act){ t = types[i]; r = atomicAdd(&hist[t], 1); }
  __syncthreads();
  if(threadIdx.x < NTY && hist[threadIdx.x] > 0)
    base[threadIdx.x] = atomicAdd(&cnts[threadIdx.x], hist[threadIdx.x]);
  __syncthreads();
  if(act) idxb[t*n + base[t] + r] = i;   // stride = n
}

// ---- weight prepack: fp32 -> bf16 + MFMA B-fragment swizzle.
__global__ void k_prepack(const float* convK, const float* convV, const float* convQ,
                          const float* convO, short* Wsw){
  int m = blockIdx.x;          // 0..63
  int fam = m >> 4;
  int lt = m & 15;             // layer*4 + type
  const float* src = (fam==0?convK:fam==1?convV:fam==2?convQ:convO) + (size_t)lt*HH*HH;
  short* dst = Wsw + (size_t)m*16384;
  for(int s=0;s<64;s++){
    int i = threadIdx.x + 256*s;
    int j = i & 7, lane = (i>>3)&63, kc = (i>>9)&3, nt = i>>11;
    int k = kc*32 + (lane>>4)*8 + j;
    int n = nt*16 + (lane&15);
    dst[i] = f2bf(src[k*HH+n]);
  }
}

// ---- K+V projection via MFMA: 32-node tile, fused LN+time-mod, bf16 in / fp32 acc.
__global__ void k_gemm_kv5(const float* X, const int* src_nid,
                           const float* dia_w, const float* dia_b,
                           const int* idxb, const int* cnts, int stride,
                           const bfrag* WK, const bfrag* WV, unsigned* KVp){
  int t = blockIdx.y;
  int cnt = cnts[t];
  int base = blockIdx.x * 32;
  if(base >= cnt || cnt == 0) return;
  int nn = min(32, cnt - base);
  const int* ids = idxb + (size_t)t*stride + base;
  __shared__ float xs[32*132];
  __shared__ float red[512];
  __shared__ float mean_s[32], inv_s[32];
  __shared__ int sid[32], nid[32];
  int tid = threadIdx.x;
  if(tid < 32){
    int s_ = (tid < nn) ? ids[tid] : ids[0];
    sid[tid] = s_; nid[tid] = src_nid[s_];
  }
  __syncthreads();
  #pragma unroll
  for(int s=0;s<16;s++){
    int elem = tid + 256*s;
    int k = elem & 127, j = elem >> 7;
    xs[j*132 + k] = X[(size_t)sid[j]*HH + k];
  }
  __syncthreads();
  {
    int j = tid >> 3, p = tid & 7;
    float sm=0.f, sq=0.f;
    const float* xr = xs + j*132 + p*16;
    #pragma unroll
    for(int i=0;i<16;i++){ float v = xr[i]; sm += v; sq += v*v; }
    red[j*8+p] = sm; red[256 + j*8+p] = sq;
  }
  __syncthreads();
  if(tid < 32){
    float sm=0.f, sq=0.f;
    #pragma unroll
    for(int p=0;p<8;p++){ sm += red[tid*8+p]; sq += red[256+tid*8+p]; }
    float mean = sm*(1.f/128.f);
    float var = sq*(1.f/128.f) - mean*mean;
    mean_s[tid] = mean;
    inv_s[tid] = 1.f/sqrtf(fmaxf(var,0.f)+1e-5f);
  }
  __syncthreads();
  #pragma unroll
  for(int s=0;s<16;s++){
    int elem = tid + 256*s;
    int k = elem & 127, j = elem >> 7;
    float v = (xs[j*132+k] - mean_s[j]) * inv_s[j];
    if(k >= D2C) v *= sinf(dia_w[(size_t)nid[j]*HH+k] + dia_b[(size_t)nid[j]*HH+k]);
    xs[j*132+k] = v;
  }
  __syncthreads();
  int lane = tid & 63, w = tid >> 6;
  int mt = w & 1, ng0 = (w>>1)*4;
  int arow = mt*16 + (lane & 15);
  int koff = (lane >> 4)*8;
  int tb = t*2048;
  ffrag aK[4], aV[4];
  #pragma unroll
  for(int i=0;i<4;i++){ aK[i] = (ffrag){0.f,0.f,0.f,0.f}; aV[i] = (ffrag){0.f,0.f,0.f,0.f}; }
  #pragma unroll
  for(int kc=0;kc<4;kc++){
    const float* ap = xs + arow*132 + kc*32 + koff;
    bfrag a;
    #pragma unroll
    for(int j=0;j<8;j++) a[j] = f2bf(ap[j]);
    #pragma unroll
    for(int nt=0;nt<4;nt++){
      int fi = tb + ((ng0+nt)*4 + kc)*64 + lane;
      bfrag bk = WK[fi];
      bfrag bv = WV[fi];
      aK[nt] = __builtin_amdgcn_mfma_f32_16x16x32_bf16(a, bk, aK[nt], 0, 0, 0);
      aV[nt] = __builtin_amdgcn_mfma_f32_16x16x32_bf16(a, bv, aV[nt], 0, 0, 0);
    }
  }
  int col0 = lane & 15;
  int rb = mt*16 + (lane>>4)*4;
  #pragma unroll
  for(int nt=0;nt<4;nt++){
    int col = (ng0+nt)*16 + col0;
    #pragma unroll
    for(int i=0;i<4;i++){
      int n = rb + i;
      if(n < nn){
        unsigned pk = (unsigned short)f2bf(aK[nt][i]);
        unsigned pv = (unsigned short)f2bf(aV[nt][i]);
        KVp[(size_t)sid[n]*HH + col] = (pv<<16) | pk;
      }
    }
  }
}

// ---- single-matrix projection via MFMA (Q: do_ln=1; O: resid+relu, optional copy).
__global__ void k_gemm_t5(const float* X, const int* idxb, const int* cnts, int stride,
                          const bfrag* W, const float* resid, float* Y, float* Y2,
                          int relu, int do_ln){
  int t = blockIdx.y;
  int cnt = cnts[t];
  int base = blockIdx.x * 32;
  if(base >= cnt || cnt == 0) return;
  int nn = min(32, cnt - base);
  const int* ids = idxb + (size_t)t*stride + base;
  __shared__ float xs[32*132];
  __shared__ float red[512];
  __shared__ float mean_s[32], inv_s[32];
  __shared__ int sid[32];
  int tid = threadIdx.x;
  if(tid < 32) sid[tid] = (tid < nn) ? ids[tid] : ids[0];
  __syncthreads();
  #pragma unroll
  for(int s=0;s<16;s++){
    int elem = tid + 256*s;
    int k = elem & 127, j = elem >> 7;
    xs[j*132 + k] = X[(size_t)sid[j]*HH + k];
  }
  __syncthreads();
  if(do_ln){
    {
      int j = tid >> 3, p = tid & 7;
      float sm=0.f, sq=0.f;
      const float* xr = xs + j*132 + p*16;
      #pragma unroll
      for(int i=0;i<16;i++){ float v = xr[i]; sm += v; sq += v*v; }
      red[j*8+p] = sm; red[256 + j*8+p] = sq;
    }
    __syncthreads();
    if(tid < 32){
      float sm=0.f, sq=0.f;
      #pragma unroll
      for(int p=0;p<8;p++){ sm += red[tid*8+p]; sq += red[256+tid*8+p]; }
      float mean = sm*(1.f/128.f);
      float var = sq*(1.f/128.f) - mean*mean;
      mean_s[tid] = mean;
      inv_s[tid] = 1.f/sqrtf(fmaxf(var,0.f)+1e-5f);
    }
    __syncthreads();
    #pragma unroll
    for(int s=0;s<16;s++){
      int elem = tid + 256*s;
      int k = elem & 127, j = elem >> 7;
      xs[j*132+k] = (xs[j*132+k] - mean_s[j]) * inv_s[j];
    }
    __syncthreads();
  }
  int lane = tid & 63, w = tid >> 6;
  int mt = w & 1, ng0 = (w>>1)*4;
  int arow = mt*16 + (lane & 15);
  int koff = (lane >> 4)*8;
  int tb = t*2048;
  ffrag acc[4];
  #pragma unroll
  for(int i=0;i<4;i++) acc[i] = (ffrag){0.f,0.f,0.f,0.f};
  #pragma unroll
  for(int kc=0;kc<4;kc++){
    const float* ap = xs + arow*132 + kc*32 + koff;
    bfrag a;
    #pragma unroll
    for(int j=0;j<8;j++) a[j] = f2bf(ap[j]);
    #pragma unroll
    for(int nt=0;nt<4;nt++){
      bfrag b = W[tb + ((ng0+nt)*4 + kc)*64 + lane];
      acc[nt] = __builtin_amdgcn_mfma_f32_16x16x32_bf16(a, b, acc[nt], 0, 0, 0);
    }
  }
  int col0 = lane & 15;
  int rb = mt*16 + (lane>>4)*4;
  #pragma unroll
  for(int nt=0;nt<4;nt++){
    int col = (ng0+nt)*16 + col0;
    #pragma unroll
    for(int i=0;i<4;i++){
      int n = rb + i;
      if(n < nn){
        size_t r = (size_t)sid[n]*HH + col;
        float v = acc[nt][i];
        if(resid){
          v += resid[r];
          if(relu) v = fmaxf(v, 0.f);
        }
        Y[r] = v;
        if(Y2) Y2[r] = v;
      }
    }
  }
}

// EW2all[layer][50][128] = edge_emb @ convE[layer]
__global__ void k_edge_tab4(const float* edge_emb, const float* convE, float* EW2all){
  int r = blockIdx.x; int layer = blockIdx.y; int o = threadIdx.x;
  const float* EWp = convE + (size_t)layer*32*HH;
  float acc = 0.f;
  for(int j=0;j<32;j++) acc += edge_emb[r*32+j]*EWp[j*HH+o];
  EW2all[((size_t)layer*50 + r)*HH + o] = acc;
}

// ---------------- CSR build (per graph) ----------------
__global__ void k_hist_dst(const int* edst, int E, int* cnt){
  int e = blockIdx.x*256 + threadIdx.x;
  if(e < E) atomicAdd(&cnt[edst[e]], 1);
}
__global__ void k_scan(const int* cnt, int n, int* row_ptr, int* cursor){
  __shared__ int tsum[1024];
  int tid = threadIdx.x;
  int per = (n + 1023) / 1024;
  int start = tid*per; int end = min(start+per, n);
  int s = 0;
  for(int i=start;i<end;i++) s += cnt[i];
  tsum[tid] = s; __syncthreads();
  for(int off=1;off<1024;off<<=1){
    int v = (tid>=off) ? tsum[tid-off] : 0;
    __syncthreads();
    tsum[tid] += v;
    __syncthreads();
  }
  int run = (tid==0) ? 0 : tsum[tid-1];
  for(int i=start;i<end;i++){ row_ptr[i]=run; cursor[i]=run; run += cnt[i]; }
  if(end == n) row_ptr[n] = run;
}
__global__ void k_fill_csr(const int* edst, int E, int* cursor, int* eid){
  int e = blockIdx.x*256 + threadIdx.x;
  if(e >= E) return;
  int pos = atomicAdd(&cursor[edst[e]], 1);
  eid[pos] = e;
}
__global__ void k_permute_edges(const int* eid, const int* esrc, const int* ew, const int* ety,
                                int E, int* esrc_s, int* ew_s, int* ety_s){
  int r = blockIdx.x*256 + threadIdx.x;
  if(r >= E) return;
  int e = eid[r];
  esrc_s[r] = esrc[e]; ew_s[r] = ew[e]; ety_s[r] = ety[e];
}

// single-pass attention on packed bf16 KV; 4-edge ILP to cover gather latency.
__global__ void k_attn_fused4(const int* __restrict__ row_ptr, const int* __restrict__ esrc_s,
                              const int* __restrict__ ew_s, const int* __restrict__ ety_s,
                              const unsigned* __restrict__ KVp, const float* __restrict__ Qbuf,
                              const float* __restrict__ EW2, const float* __restrict__ mu,
                              float* __restrict__ Abuf){
  int d = blockIdx.x; int o = threadIdx.x;
  int r0 = row_ptr[d], r1 = row_ptr[d+1];
  __shared__ float q[HH];
  q[o] = Qbuf[(size_t)d*HH+o];
  __syncthreads();
  int h = o >> 4;
  float qo = q[o];
  float dn0=0.f, dn1=0.f, dn2=0.f, dn3=0.f;
  float ac0=0.f, ac1=0.f, ac2=0.f, ac3=0.f;
  int r = r0;
  for(; r+3 < r1; r += 4){
    int s0=esrc_s[r], s1=esrc_s[r+1], s2=esrc_s[r+2], s3=esrc_s[r+3];
    int w0=ew_s[r],   w1=ew_s[r+1],   w2=ew_s[r+2],   w3=ew_s[r+3];
    int t0=ety_s[r],  t1=ety_s[r+1],  t2=ety_s[r+2],  t3=ety_s[r+3];
    unsigned uA = KVp[(size_t)s0*HH + o];
    unsigned uB = KVp[(size_t)s1*HH + o];
    unsigned uC = KVp[(size_t)s2*HH + o];
    unsigned uD = KVp[(size_t)s3*HH + o];
    float eA = EW2[w0*HH+o], eB = EW2[w1*HH+o], eC = EW2[w2*HH+o], eD = EW2[w3*HH+o];
    float kA = __uint_as_float(uA<<16), vA = __uint_as_float(uA & 0xffff0000u);
    float kB = __uint_as_float(uB<<16), vB = __uint_as_float(uB & 0xffff0000u);
    float kC = __uint_as_float(uC<<16), vC = __uint_as_float(uC & 0xffff0000u);
    float kD = __uint_as_float(uD<<16), vD = __uint_as_float(uD & 0xffff0000u);
    float pA = qo*(kA + eA);
    float pB = qo*(kB + eB);
    float pC = qo*(kC + eC);
    float pD = qo*(kD + eD);
    pA += __shfl_xor(pA, 1, 64); pB += __shfl_xor(pB, 1, 64);
    pC += __shfl_xor(pC, 1, 64); pD += __shfl_xor(pD, 1, 64);
    pA += __shfl_xor(pA, 2, 64); pB += __shfl_xor(pB, 2, 64);
    pC += __shfl_xor(pC, 2, 64); pD += __shfl_xor(pD, 2, 64);
    pA += __shfl_xor(pA, 4, 64); pB += __shfl_xor(pB, 4, 64);
    pC += __shfl_xor(pC, 4, 64); pD += __shfl_xor(pD, 4, 64);
    pA += __shfl_xor(pA, 8, 64); pB += __shfl_xor(pB, 8, 64);
    pC += __shfl_xor(pC, 8, 64); pD += __shfl_xor(pD, 8, 64);
    float sA = pA * mu[t0*NH+h] * 0.25f;
    float sB = pB * mu[t1*NH+h] * 0.25f;
    float sC = pC * mu[t2*NH+h] * 0.25f;
    float sD = pD * mu[t3*NH+h] * 0.25f;
    float e0 = __expf(sA), e1 = __expf(sB), e2 = __expf(sC), e3 = __expf(sD);
    dn0 += e0; ac0 += e0*vA;
    dn1 += e1; ac1 += e1*vB;
    dn2 += e2; ac2 += e2*vC;
    dn3 += e3; ac3 += e3*vD;
  }
  for(; r+1 < r1; r += 2){
    unsigned uA = KVp[(size_t)esrc_s[r]*HH + o];
    unsigned uB = KVp[(size_t)esrc_s[r+1]*HH + o];
    float eA = EW2[ew_s[r]*HH+o];
    float eB = EW2[ew_s[r+1]*HH+o];
    float kA = __uint_as_float(uA<<16), vA = __uint_as_float(uA & 0xffff0000u);
    float kB = __uint_as_float(uB<<16), vB = __uint_as_float(uB & 0xffff0000u);
    float pA = qo*(kA + eA);
    float pB = qo*(kB + eB);
    pA += __shfl_xor(pA, 1, 64);  pB += __shfl_xor(pB, 1, 64);
    pA += __shfl_xor(pA, 2, 64);  pB += __shfl_xor(pB, 2, 64);
    pA += __shfl_xor(pA, 4, 64);  pB += __shfl_xor(pB, 4, 64);
    pA += __shfl_xor(pA, 8, 64);  pB += __shfl_xor(pB, 8, 64);
    float sA = pA * mu[ety_s[r]*NH+h] * 0.25f;
    float sB = pB * mu[ety_s[r+1]*NH+h] * 0.25f;
    float e0 = __expf(sA), e1 = __expf(sB);
    dn0 += e0; ac0 += e0*vA;
    dn1 += e1; ac1 += e1*vB;
  }
  if(r < r1){
    unsigned uA = KVp[(size_t)esrc_s[r]*HH + o];
    float kA = __uint_as_float(uA<<16), vA = __uint_as_float(uA & 0xffff0000u);
    float pA = qo*(kA + EW2[ew_s[r]*HH+o]);
    pA += __shfl_xor(pA, 1, 64);
    pA += __shfl_xor(pA, 2, 64);
    pA += __shfl_xor(pA, 4, 64);
    pA += __shfl_xor(pA, 8, 64);
    float sA = pA * mu[ety_s[r]*NH+h] * 0.25f;
    float e0 = __expf(sA);
    dn0 += e0; ac0 += e0*vA;
  }
  float dd = (dn0+dn1)+(dn2+dn3), acc = (ac0+ac1)+(ac2+ac3);
  Abuf[(size_t)d*HH + o] = acc / fmaxf(dd, 1e-9f);
}

// ---------------- stage D: token pooling ----------------
__global__ void k_zero_hist(float* hist2, float* cnt, unsigned* amax, float* aden){
  int i = blockIdx.x*blockDim.x + threadIdx.x;
  if(i < CHILDN*HH) hist2[i] = 0.f;
  if(i < CHILDN){ cnt[i] = 0.f; aden[i] = 0.f; amax[i] = 0x007FFFFFu; }
}

__global__ void k_tokatt(const float* h2f, const int* toknt, const float* ipW, const float* iaW,
                         float* abuf, unsigned* amax, const int* tokid){
  int t = blockIdx.x; int o = threadIdx.x;
  __shared__ float es[HH];
  __shared__ float red[HH];
  int b = t % BB, l = t / BB;
  es[o] = h2f[(b*LL+l)*HH+o];
  __syncthreads();
  int nt = toknt[t];
  const float* w = ipW + (size_t)nt*HH*HH;
  float acc = 0.f;
  for(int j=0;j<HH;j++) acc += es[j]*w[j*HH+o];
  float u = tanhf(acc);
  red[o] = u * iaW[nt*HH+o];
  __syncthreads();
  for(int s=64;s>0;s>>=1){ if(o<s) red[o]+=red[o+s]; __syncthreads(); }
  if(o==0){
    float a = red[0];
    abuf[t] = a;
    atomicMax(&amax[tokid[t]], fenc(a));
  }
}

__global__ void k_tokexp(const int* tokid, float* abuf, const unsigned* amax, float* aden, float* cnt){
  int t = blockIdx.x*blockDim.x + threadIdx.x;
  if(t >= TT) return;
  int c = tokid[t];
  float ex = expf(abuf[t]-fdec(amax[c]));
  abuf[t] = ex;
  atomicAdd(&aden[c], ex);
  atomicAdd(&cnt[c], 1.f);
}

__global__ void k_tokagg(const int* tokid, const float* abuf, const float* aden,
                         const float* h2f, float* hist2){
  int t = blockIdx.x; int o = threadIdx.x;
  int c = tokid[t];
  float w = abuf[t]/fmaxf(aden[c],1e-9f);
  int b = t % BB, l = t / BB;
  atomicAdd(&hist2[c*HH+o], w*h2f[(b*LL+l)*HH+o]);
}

__global__ void k_histfix(const float* cnt, const float* hist_emb, float* hist2){
  int c = blockIdx.x; int o = threadIdx.x;
  if(cnt[c] == 0.f) hist2[c*HH+o] = hist_emb[c*HH+o];
}

// ---------------- parent pooling ----------------
__global__ void k_zero_parent(float* psum, float* pcnt){
  int i = blockIdx.x*blockDim.x + threadIdx.x;
  if(i < PARENTN*HH) psum[i] = 0.f;
  if(i < PARENTN) pcnt[i] = 0.f;
}

__global__ void k_peagg(const int* pe_p, const int* pe_c, const float* cef, float* psum, float* pcnt){
  int i = blockIdx.x; int o = threadIdx.x;
  int p = pe_p[i], c = pe_c[i];
  atomicAdd(&psum[p*HH+o], cef[c*HH+o]);
  if(o==0) atomicAdd(&pcnt[p], 1.f);
}

__global__ void k_parent(const float* psum, const float* pcnt, float* out){
  int i = blockIdx.x; int o = threadIdx.x;
  out[i*HH+o] = psum[i*HH+o]/fmaxf(pcnt[i],1.f);
}

extern "C" void kernel_launch(void* const* d_in, const int* in_sizes, int n_in,
                              void* d_out, int out_size, void* d_ws, size_t ws_size,
                              hipStream_t stream){
  const int* seq     = (const int*)d_in[0];
  const int* seq_nt  = (const int*)d_in[1];
  const int* dur     = (const int*)d_in[2];
  const int* stime   = (const int*)d_in[3];
  const int* etime   = (const int*)d_in[4];
  const int* g1_nid  = (const int*)d_in[5];
  const int* g1_nt   = (const int*)d_in[6];
  const int* g1_esrc = (const int*)d_in[7];
  const int* g1_edst = (const int*)d_in[8];
  const int* g1_ety  = (const int*)d_in[9];
  const int* g1_ew   = (const int*)d_in[10];
  const int* g2_sel  = (const int*)d_in[11];
  const int* g2_esrc = (const int*)d_in[12];
  const int* g2_edst = (const int*)d_in[13];
  const int* g2_ety  = (const int*)d_in[14];
  const int* g2_ew   = (const int*)d_in[15];
  const int* tok_sel = (const int*)d_in[16];
  const int* g4_esrc = (const int*)d_in[17];
  const int* g4_edst = (const int*)d_in[18];
  const int* g4_ety  = (const int*)d_in[19];
  const int* g4_ew   = (const int*)d_in[20];
  const int* pe_p    = (const int*)d_in[21];
  const int* pe_c    = (const int*)d_in[22];
  const float* emb     = (const float*)d_in[23];
  const float* hist_emb= (const float*)d_in[24];
  const float* edge_emb= (const float*)d_in[25];
  const float* dia_w   = (const float*)d_in[26];
  const float* dia_b   = (const float*)d_in[27];
  const float* t2v_w   = (const float*)d_in[28];
  const float* t2v_b   = (const float*)d_in[29];
  const float* exp_W   = (const float*)d_in[30];
  const float* exp_b   = (const float*)d_in[31];
  const float* l1Wi    = (const float*)d_in[32];
  const float* l1Wh    = (const float*)d_in[33];
  const float* l1b     = (const float*)d_in[34];
  const float* l2Wi    = (const float*)d_in[35];
  const float* l2Wh    = (const float*)d_in[36];
  const float* l2b     = (const float*)d_in[37];
  const float* convK   = (const float*)d_in[38];
  const float* convQ   = (const float*)d_in[39];
  const float* convV   = (const float*)d_in[40];
  const float* convO   = (const float*)d_in[41];
  const float* convE   = (const float*)d_in[42];
  const float* convMu  = (const float*)d_in[43];
  const float* ipW     = (const float*)d_in[44];
  const float* iaW     = (const float*)d_in[45];
  const float* skip    = (const float*)d_in[46];
  float* outp = (float*)d_out;

  // workspace arena
  char* wsp = (char*)d_ws;
  size_t off = 0;
  auto A = [&](size_t nbytes)->char*{ char* p = wsp+off; off += (nbytes+255)&~(size_t)255; return p; };
  float*    srcbuf = (float*)   A((size_t)N1SN*HH*4);
  unsigned* KVp    = (unsigned*)A((size_t)N1SN*HH*4);    // packed bf16 [V|K]
  float*    Qbuf   = (float*)   A((size_t)N1DN*HH*4);
  float*    Abuf   = (float*)   A((size_t)N1DN*HH*4);
  float*    xbuf   = (float*)   A((size_t)TT*HH*4);
  float*    gpre   = (float*)   A((size_t)TT*512*4);
  float*    h1     = (float*)   A((size_t)TT*HH*4);
  float*    dst2   = (float*)   A((size_t)TT*HH*4);
  float*    xg     = (float*)   A((size_t)N1DN*HH*4);
  float*    x2     = (float*)   A((size_t)TT*HH*4);
  float*    h2f    = (float*)   A((size_t)TT*HH*4);
  float*    hist2  = (float*)   A((size_t)CHILDN*HH*4);
  float*    cnt    = (float*)   A((size_t)CHILDN*4);
  float*    abuf   = (float*)   A((size_t)TT*4);
  unsigned* amax   = (unsigned*)A((size_t)CHILDN*4);
  float*    aden   = (float*)   A((size_t)CHILDN*4);
  float*    x3     = (float*)   A((size_t)N1DN*HH*4);
  float*    cef    = (float*)   A((size_t)N4DN*HH*4);
  float*    psum   = (float*)   A((size_t)PARENTN*HH*4);
  float*    pcnt   = (float*)   A((size_t)PARENTN*4);
  int*      tokid  = (int*)     A((size_t)TT*4);
  int*      toknt  = (int*)     A((size_t)TT*4);
  int*      gnid2  = (int*)     A((size_t)N2N*4);
  int*      tsrc2  = (int*)     A((size_t)N2N*4);
  int*      idxS1  = (int*)     A((size_t)NTY*N1SN*4);
  int*      idxS2  = (int*)     A((size_t)NTY*N1DN*4);
  int*      idxS3  = (int*)     A((size_t)NTY*N2N*4);
  int*      idxS4  = (int*)     A((size_t)NTY*TT*4);
  int*      idxS5  = (int*)     A((size_t)NTY*N4DN*4);
  int*      cntall = (int*)     A((size_t)5*NTY*4);
  float*    EW2all = (float*)   A((size_t)4*50*HH*4);
  short*    Wsw    = (short*)   A((size_t)64*16384*2);   // bf16-swizzled weights
  int*      g1row  = (int*)     A((size_t)(N1DN+1)*4);
  int*      g1eid  = (int*)     A((size_t)E1N*4);
  int*      g1src_s= (int*)     A((size_t)E1N*4);
  int*      g1ew_s = (int*)     A((size_t)E1N*4);
  int*      g1ety_s= (int*)     A((size_t)E1N*4);
  int*      g2row  = (int*)     A((size_t)(TT+1)*4);
  int*      g2eid  = (int*)     A((size_t)E2N*4);
  int*      g2src_s= (int*)     A((size_t)E2N*4);
  int*      g2ew_s = (int*)     A((size_t)E2N*4);
  int*      g2ety_s= (int*)     A((size_t)E2N*4);
  int*      g4row  = (int*)     A((size_t)(N4DN+1)*4);
  int*      g4eid  = (int*)     A((size_t)E4N*4);
  int*      g4src_s= (int*)     A((size_t)E4N*4);
  int*      g4ew_s = (int*)     A((size_t)E4N*4);
  int*      g4ety_s= (int*)     A((size_t)E4N*4);
  int*      icnt   = (int*)     A((size_t)(N1DN+1)*4);
  int*      icur   = (int*)     A((size_t)(N1DN+1)*4);
  if(off > ws_size) return;  // insufficient scratch: output stays zero

  auto build_csr = [&](const int* edst, const int* esrc, const int* ew, const int* ety,
                       int E, int ndst, int* rowp, int* eid, int* src_s, int* ew_s, int* ety_s){
    k_zero_intk<<<(ndst+255)/256, 256, 0, stream>>>(icnt, ndst);
    k_hist_dst<<<(E+255)/256, 256, 0, stream>>>(edst, E, icnt);
    k_scan<<<1, 1024, 0, stream>>>(icnt, ndst, rowp, icur);
    k_fill_csr<<<(E+255)/256, 256, 0, stream>>>(edst, E, icur, eid);
    k_permute_edges<<<(E+255)/256, 256, 0, stream>>>(eid, esrc, ew, ety, E, src_s, ew_s, ety_s);
  };

  auto run_conv = [&](const float* src_h, const int* src_nid, int nsrc,
                      const int* idx_src, int* cnt_src, int stride_src,
                      const float* dst_h, int ndst,
                      const int* idx_dst, int* cnt_dst, int stride_dst,
                      const int* rowp, const int* src_s, const int* ew_s, const int* ety_s,
                      int layer, float* outbuf, float* out2, int relu){
    const bfrag* WB = (const bfrag*)Wsw;
    const bfrag* WK = WB + (size_t)( 0 + layer*4)*2048;
    const bfrag* WV = WB + (size_t)(16 + layer*4)*2048;
    const bfrag* WQ = WB + (size_t)(32 + layer*4)*2048;
    const bfrag* WO = WB + (size_t)(48 + layer*4)*2048;
    const float* MU  = convMu + (size_t)layer*NRL*NH;
    const float* EW2 = EW2all + (size_t)layer*50*HH;
    dim3 gkv((nsrc+31)/32, NTY);
    k_gemm_kv5<<<gkv, 256, 0, stream>>>(src_h, src_nid, dia_w, dia_b,
                                        idx_src, cnt_src, stride_src, WK, WV, KVp);
    dim3 gq((ndst+31)/32, NTY);
    k_gemm_t5<<<gq, 256, 0, stream>>>(dst_h, idx_dst, cnt_dst, stride_dst, WQ,
                                      (const float*)nullptr, Qbuf, (float*)nullptr, 0, 1);
    k_attn_fused4<<<ndst, HH, 0, stream>>>(rowp, src_s, ew_s, ety_s, KVp, Qbuf, EW2, MU, Abuf);
    k_gemm_t5<<<gq, 256, 0, stream>>>(Abuf, idx_dst, cnt_dst, stride_dst, WO,
                                      dst_h, outbuf, out2, relu, 0);
  };

  // ---- stage A: features + LSTM1 (fused scan) ----
  k_featx2<<<TT/32, 512, 0, stream>>>(seq, dur, stime, etime, emb, dia_w, dia_b, t2v_w, t2v_b, exp_W, exp_b, xbuf);
  k_xwi2<<<(TT+15)/16, 256, 0, stream>>>(xbuf, l1Wi, l1b, gpre, TT, 0);
  k_lstm_fused<<<BB, 512, 0, stream>>>(gpre, l1Wh, h1, (float*)nullptr);
  k_tok<<<(TT+255)/256, 256, 0, stream>>>(seq, seq_nt, tokid, toknt);

  // ---- upfront: weight prepack, edge tables, type scatters, g1 CSR ----
  k_prepack<<<64, 256, 0, stream>>>(convK, convV, convQ, convO, Wsw);
  k_edge_tab4<<<dim3(50,4), HH, 0, stream>>>(edge_emb, convE, EW2all);
  k_zero_intk<<<1, 64, 0, stream>>>(cntall, 5*NTY);
  k_scatter_type<<<(N1SN+255)/256, 256, 0, stream>>>(g1_nt, N1SN, cntall+0*NTY, idxS1);
  k_scatter_type<<<(N1DN+255)/256, 256, 0, stream>>>(g1_nt, N1DN, cntall+1*NTY, idxS2);
  k_scatter_type<<<(TT+255)/256, 256, 0, stream>>>(toknt, TT, cntall+3*NTY, idxS4);
  k_scatter_type<<<(N4DN+255)/256, 256, 0, stream>>>(g1_nt, N4DN, cntall+4*NTY, idxS5);
  build_csr(g1_edst, g1_esrc, g1_ew, g1_ety, E1N, N1DN, g1row, g1eid, g1src_s, g1ew_s, g1ety_s);

  // ---- conv1 on g1 ----
  k_gather_emb<<<N1SN, HH, 0, stream>>>(g1_nid, emb, srcbuf);
  run_conv(srcbuf, g1_nid, N1SN, idxS1, cntall+0*NTY, N1SN,
           srcbuf, N1DN, idxS2, cntall+1*NTY, N1DN,
           g1row, g1src_s, g1ew_s, g1ety_s, 0, xg, (float*)nullptr, 1);

  // ---- conv2 on g2 ----
  build_csr(g2_edst, g2_esrc, g2_ew, g2_ety, E2N, TT, g2row, g2eid, g2src_s, g2ew_s, g2ety_s);
  k_prep2<<<N2N, HH, 0, stream>>>(g2_sel, xg, g1_nid, g1_nt, srcbuf, gnid2, tsrc2);
  k_scatter_type<<<(N2N+255)/256, 256, 0, stream>>>(tsrc2, N2N, cntall+2*NTY, idxS3);
  k_dst2<<<TT, HH, 0, stream>>>(tok_sel, xg, h1, dst2);
  run_conv(srcbuf, gnid2, N2N, idxS3, cntall+2*NTY, N2N,
           dst2, TT, idxS4, cntall+3*NTY, TT,
           g2row, g2src_s, g2ew_s, g2ety_s, 1, x2, (float*)nullptr, 1);

  // ---- LSTM2 (h2 is output 0); x2 read directly with permuted layout ----
  k_xwi2<<<(TT+15)/16, 256, 0, stream>>>(x2, l2Wi, l2b, gpre, TT, 1);
  k_lstm_fused<<<BB, 512, 0, stream>>>(gpre, l2Wh, h2f, outp);

  // ---- stage D: token attention pooling -> hist2 ----
  k_zero_hist<<<(CHILDN*HH+255)/256, 256, 0, stream>>>(hist2, cnt, amax, aden);
  k_tokatt<<<TT, HH, 0, stream>>>(h2f, toknt, ipW, iaW, abuf, amax, tokid);
  k_tokexp<<<(TT+255)/256, 256, 0, stream>>>(tokid, abuf, amax, aden, cnt);
  k_tokagg<<<TT, HH, 0, stream>>>(tokid, abuf, aden, h2f, hist2);
  k_histfix<<<CHILDN, HH, 0, stream>>>(cnt, hist_emb, hist2);

  // ---- conv3 on g1 with skip-mixed input (g1 CSR + scatters reused) ----
  k_x0<<<N1SN, HH, 0, stream>>>(g1_nid, g1_nt, emb, hist2, skip, srcbuf);
  run_conv(srcbuf, g1_nid, N1SN, idxS1, cntall+0*NTY, N1SN,
           srcbuf, N1DN, idxS2, cntall+1*NTY, N1DN,
           g1row, g1src_s, g1ew_s, g1ety_s, 2, x3, (float*)nullptr, 1);

  // ---- conv4 on g4 (child_embed = output 1, no relu) ----
  build_csr(g4_edst, g4_esrc, g4_ew, g4_ety, E4N, N4DN, g4row, g4eid, g4src_s, g4ew_s, g4ety_s);
  run_conv(x3, g1_nid, N1DN, idxS2, cntall+1*NTY, N1DN,
           x3, N4DN, idxS5, cntall+4*NTY, N4DN,
           g4row, g4src_s, g4ew_s, g4ety_s, 3, cef, outp + (size_t)TT*HH, 0);

  // ---- parent pooling (output 2) ----
  k_zero_parent<<<(PARENTN*HH+255)/256, 256, 0, stream>>>(psum, pcnt);
  k_peagg<<<EC2PN, HH, 0, stream>>>(pe_p, pe_c, cef, psum, pcnt);
  k_parent<<<PARENTN, HH, 0, stream>>>(psum, pcnt, outp + (size_t)TT*HH + (size_t)N4DN*HH);
}

// Round 2
// 873.343 us; speedup vs baseline: 1.2400x; 1.0456x over previous
//
#include <hip/hip_runtime.h>
#include <math.h>

#define BB 256
#define LL 20
#define HH 128
#define NH 8
#define D2C 64
#define NTY 4
#define NRL 4
#define CHILDN 30001
#define PARENTN 500
#define N1SN 50000
#define N1DN 20000
#define E1N 300000
#define N2N 20000
#define E2N 200000
#define TT (BB*LL)
#define N4DN 5000
#define E4N 150000
#define EC2PN 8000

typedef __attribute__((ext_vector_type(8))) short bfrag;   // 8 bf16 in 4 VGPRs
typedef __attribute__((ext_vector_type(4))) float ffrag;   // MFMA accumulator

__device__ __forceinline__ unsigned fenc(float f){ unsigned u=__float_as_uint(f); return (u&0x80000000u)? ~u : (u|0x80000000u); }
__device__ __forceinline__ float fdec(unsigned u){ return (u&0x80000000u)? __uint_as_float(u^0x80000000u) : __uint_as_float(~u); }
__device__ __forceinline__ float sigf(float x){ return 1.f/(1.f+expf(-x)); }
__device__ __forceinline__ float sigfast(float x){ return 1.f/(1.f+__expf(-x)); }
__device__ __forceinline__ float tanhfast(float x){ float e = __expf(-2.f*x); return (1.f-e)/(1.f+e); }
__device__ __forceinline__ short f2bf(float f){
  unsigned u = __float_as_uint(f);
  unsigned r = u + 0x7FFFu + ((u>>16)&1u);   // round-to-nearest-even
  return (short)(r>>16);
}

// ---------------- Stage A: feature expansion (tiled: 32 tokens/block) ----------------
__global__ __launch_bounds__(512) void k_featx2(const int* __restrict__ seq, const int* __restrict__ dur,
                        const int* __restrict__ stime, const int* __restrict__ etime,
                        const float* __restrict__ emb, const float* __restrict__ dia_w, const float* __restrict__ dia_b,
                        const float* __restrict__ t2v_w, const float* __restrict__ t2v_b,
                        const float* __restrict__ exp_W, const float* __restrict__ exp_b, float* __restrict__ xout){
  __shared__ float feat[32*273];           // [st(128) | et(128) | tv(16)] per token, stride 273
  int base = blockIdx.x*32;
  int j = threadIdx.x >> 4;                // token 0..31
  int p = threadIdx.x & 15;                // 16 threads/token, 8 cols each
  int row = base + j;
  int node = seq[row];
  float ts = (float)stime[row], te = (float)etime[row];
  const float* ep = emb + (size_t)node*HH;
  float* fr = feat + j*273;
  int o0 = p*8;
  #pragma unroll
  for(int ii=0; ii<8; ii+=4){
    int o = o0 + ii;
    float4 e = *(const float4*)(ep + o);
    float4 st = e, et = e;
    if(o >= D2C){
      float4 w = *(const float4*)(dia_w + (size_t)node*HH + o);
      float4 b = *(const float4*)(dia_b + (size_t)node*HH + o);
      st.x = e.x*sinf(w.x*ts+b.x); st.y = e.y*sinf(w.y*ts+b.y);
      st.z = e.z*sinf(w.z*ts+b.z); st.w = e.w*sinf(w.w*ts+b.w);
      et.x = e.x*sinf(w.x*te+b.x); et.y = e.y*sinf(w.y*te+b.y);
      et.z = e.z*sinf(w.z*te+b.z); et.w = e.w*sinf(w.w*te+b.w);
    }
    fr[o] = st.x; fr[o+1] = st.y; fr[o+2] = st.z; fr[o+3] = st.w;
    fr[128+o] = et.x; fr[128+o+1] = et.y; fr[128+o+2] = et.z; fr[128+o+3] = et.w;
  }
  if(p == 0){
    float td = (float)dur[row];
    #pragma unroll
    for(int i=0;i<16;i++){
      float w = t2v_w[i], b = t2v_b[i];
      fr[256+i] = (i==0) ? (w*td + b) : sinf(w*td + b);
    }
  }
  __syncthreads();
  // GEMM: 32x272 @ 272x128, each thread: 2 rows x 4 cols
  int oc = (threadIdx.x & 31)*4;
  int jg = threadIdx.x >> 5;               // 0..15
  const float* f0 = feat + (jg*2)*273;
  const float* f1 = feat + (jg*2+1)*273;
  float4 a0 = {0,0,0,0}, a1 = {0,0,0,0};
  for(int k=0;k<272;k++){
    float4 w = *(const float4*)(exp_W + (size_t)k*HH + oc);
    float x0 = f0[k], x1 = f1[k];
    a0.x += x0*w.x; a0.y += x0*w.y; a0.z += x0*w.z; a0.w += x0*w.w;
    a1.x += x1*w.x; a1.y += x1*w.y; a1.z += x1*w.z; a1.w += x1*w.w;
  }
  float4 bv = *(const float4*)(exp_b + oc);
  a0.x = fmaxf(a0.x+bv.x, 0.f); a0.y = fmaxf(a0.y+bv.y, 0.f);
  a0.z = fmaxf(a0.z+bv.z, 0.f); a0.w = fmaxf(a0.w+bv.w, 0.f);
  a1.x = fmaxf(a1.x+bv.x, 0.f); a1.y = fmaxf(a1.y+bv.y, 0.f);
  a1.z = fmaxf(a1.z+bv.z, 0.f); a1.w = fmaxf(a1.w+bv.w, 0.f);
  *(float4*)(xout + (size_t)(base + jg*2  )*HH + oc) = a0;
  *(float4*)(xout + (size_t)(base + jg*2+1)*HH + oc) = a1;
}

// tiled x @ Wi + b -> gpre: 16 rows x 512 cols per block; perm=1 reads x in (l*BB+b) layout
__global__ void k_xwi2(const float* x, const float* Wi, const float* bias, float* gpre, int rows, int perm){
  int base = blockIdx.x*16;
  __shared__ float xs[128*17];
  int tid = threadIdx.x;
  #pragma unroll
  for(int s=0;s<8;s++){
    int elem = tid + 256*s;
    int k = elem & 127, j = elem >> 7;
    int r = base + j;
    int src = r;
    if(perm) src = (r % LL)*BB + (r / LL);
    xs[k*17 + j] = (r < rows) ? x[(size_t)src*HH + k] : 0.f;
  }
  __syncthreads();
  int o4 = (tid & 127)*4;
  int ng = tid >> 7;
  float4 a[8];
  #pragma unroll
  for(int j=0;j<8;j++) a[j]=make_float4(0,0,0,0);
  for(int k=0;k<HH;k++){
    float4 w = *(const float4*)(Wi + (size_t)k*512 + o4);
    const float* xr = xs + k*17 + ng*8;
    #pragma unroll
    for(int j=0;j<8;j++){
      float xv = xr[j];
      a[j].x += xv*w.x; a[j].y += xv*w.y; a[j].z += xv*w.z; a[j].w += xv*w.w;
    }
  }
  float4 bv = *(const float4*)(bias + o4);
  #pragma unroll
  for(int j=0;j<8;j++){
    int r = base + ng*8 + j;
    if(r < rows){
      float4 v = a[j];
      v.x += bv.x; v.y += bv.y; v.z += bv.z; v.w += bv.w;
      *(float4*)(gpre + (size_t)r*512 + o4) = v;
    }
  }
}

// fused 20-step LSTM: one block per batch row, Wh column in registers, gpre
// prefetched into registers (independent of recurrence), activations spread
// across all 512 threads (1 fast-exp each).
__global__ __launch_bounds__(512, 2) void k_lstm_fused(const float* __restrict__ gpre,
                                                       const float* __restrict__ Wh,
                                                       float* __restrict__ hout,
                                                       float* __restrict__ hout2){
  int b = blockIdx.x;
  int o = threadIdx.x;
  __shared__ float hs[HH];
  __shared__ float act[512];
  float wr[HH];
  #pragma unroll
  for(int h=0;h<HH;h++) wr[h] = Wh[(size_t)h*512 + o];
  float gv[LL];
  const float* gp = gpre + (size_t)b*LL*512 + o;
  #pragma unroll
  for(int l=0;l<LL;l++) gv[l] = gp[(size_t)l*512];
  if(o < HH) hs[o] = 0.f;
  float cc = 0.f;
  int quad = o >> 7;                        // 0=i, 1=f, 2=g, 3=o
  __syncthreads();
  for(int l=0;l<LL;l++){
    float a0=0.f,a1=0.f,a2=0.f,a3=0.f;
    #pragma unroll
    for(int h=0;h<HH;h+=4){
      float4 hv = *(const float4*)&hs[h];
      a0 += hv.x*wr[h];   a1 += hv.y*wr[h+1];
      a2 += hv.z*wr[h+2]; a3 += hv.w*wr[h+3];
    }
    float g = gv[l] + ((a0+a1)+(a2+a3));
    act[o] = (quad==2) ? tanhfast(g) : sigfast(g);
    __syncthreads();
    if(o < HH){
      cc = act[HH+o]*cc + act[o]*act[2*HH+o];
      float hh = act[3*HH+o]*tanhfast(cc);
      hs[o] = hh;
      size_t bi = ((size_t)b*LL + l)*HH + o;
      hout[bi] = hh;
      if(hout2) hout2[bi] = hh;
    }
    __syncthreads();
  }
}

__global__ void k_tok(const int* seq, const int* seq_nt, int* tokid, int* toknt){
  int t = blockIdx.x*blockDim.x + threadIdx.x;
  if(t >= TT) return;
  int b = t % BB, l = t / BB;
  tokid[t] = seq[b*LL+l];
  toknt[t] = seq_nt[b*LL+l];
}

// ---------------- conv prep ----------------
__global__ void k_prep2i(const int* sel, const int* g1_nid, const int* g1_nt, int* gnid2, int* tsrc2){
  int i = blockIdx.x*256 + threadIdx.x;
  if(i >= N2N) return;
  int s = sel[i];
  gnid2[i] = g1_nid[s];
  tsrc2[i] = g1_nt[s];
}

__global__ void k_dst2(const int* tok_sel, const float* xg, const float* h1, float* dst2){
  int t = blockIdx.x; int o = threadIdx.x;
  int b = t % BB, l = t / BB;
  dst2[t*HH+o] = xg[tok_sel[t]*HH+o] + h1[(b*LL+l)*HH+o];
}

__global__ void k_x0(const int* nid, const int* ntype, const float* emb, const float* hist2,
                     const float* skip, float* srcbuf){
  int i = blockIdx.x; int o = threadIdx.x;
  float a = sigf(skip[ntype[i]]);
  int nd = nid[i];
  srcbuf[i*HH+o] = emb[nd*HH+o]*a + hist2[nd*HH+o]*(1.f-a);
}

__global__ void k_zero_intk(int* p, int n){
  int i = blockIdx.x*256 + threadIdx.x;
  if(i < n) p[i] = 0;
}

// block-aggregated type scatter
__global__ void k_scatter_type(const int* types, int n, int* cnts, int* idxb){
  __shared__ int hist[NTY];
  __shared__ int base[NTY];
  int i = blockIdx.x*256 + threadIdx.x;
  if(threadIdx.x < NTY) hist[threadIdx.x] = 0;
  __syncthreads();
  int t = 0, r = 0;
  bool act = (i < n);
  if(act){ t = types[i]; r = atomicAdd(&hist[t], 1); }
  __syncthreads();
  if(threadIdx.x < NTY && hist[threadIdx.x] > 0)
    base[threadIdx.x] = atomicAdd(&cnts[threadIdx.x], hist[threadIdx.x]);
  __syncthreads();
  if(act) idxb[t*n + base[t] + r] = i;   // stride = n
}

// ---- weight prepack: fp32 -> bf16 + MFMA B-fragment swizzle.
__global__ void k_prepack(const float* convK, const float* convV, const float* convQ,
                          const float* convO, short* Wsw){
  int m = blockIdx.x;          // 0..63
  int fam = m >> 4;
  int lt = m & 15;             // layer*4 + type
  const float* src = (fam==0?convK:fam==1?convV:fam==2?convQ:convO) + (size_t)lt*HH*HH;
  short* dst = Wsw + (size_t)m*16384;
  for(int s=0;s<64;s++){
    int i = threadIdx.x + 256*s;
    int j = i & 7, lane = (i>>3)&63, kc = (i>>9)&3, nt = i>>11;
    int k = kc*32 + (lane>>4)*8 + j;
    int n = nt*16 + (lane&15);
    dst[i] = f2bf(src[k*HH+n]);
  }
}

// ---- K+V projection via MFMA: 32-node tile, fused LN+time-mod, bf16 in / fp32 acc.
// rowmap (optional): X row = rowmap[graph_idx] (gathers e.g. emb[g1_nid[i]]).
__global__ void k_gemm_kv5(const float* X, const int* src_nid, const int* rowmap,
                           const float* dia_w, const float* dia_b,
                           const int* idxb, const int* cnts, int stride,
                           const bfrag* WK, const bfrag* WV, unsigned* KVp){
  int t = blockIdx.y;
  int cnt = cnts[t];
  int base = blockIdx.x * 32;
  if(base >= cnt || cnt == 0) return;
  int nn = min(32, cnt - base);
  const int* ids = idxb + (size_t)t*stride + base;
  __shared__ float xs[32*132];
  __shared__ float red[512];
  __shared__ float mean_s[32], inv_s[32];
  __shared__ int sid[32], nid[32], xrow[32];
  int tid = threadIdx.x;
  if(tid < 32){
    int s_ = (tid < nn) ? ids[tid] : ids[0];
    sid[tid] = s_; nid[tid] = src_nid[s_];
    xrow[tid] = rowmap ? rowmap[s_] : s_;
  }
  __syncthreads();
  #pragma unroll
  for(int s=0;s<16;s++){
    int elem = tid + 256*s;
    int k = elem & 127, j = elem >> 7;
    xs[j*132 + k] = X[(size_t)xrow[j]*HH + k];
  }
  __syncthreads();
  {
    int j = tid >> 3, p = tid & 7;
    float sm=0.f, sq=0.f;
    const float* xr = xs + j*132 + p*16;
    #pragma unroll
    for(int i=0;i<16;i++){ float v = xr[i]; sm += v; sq += v*v; }
    red[j*8+p] = sm; red[256 + j*8+p] = sq;
  }
  __syncthreads();
  if(tid < 32){
    float sm=0.f, sq=0.f;
    #pragma unroll
    for(int p=0;p<8;p++){ sm += red[tid*8+p]; sq += red[256+tid*8+p]; }
    float mean = sm*(1.f/128.f);
    float var = sq*(1.f/128.f) - mean*mean;
    mean_s[tid] = mean;
    inv_s[tid] = 1.f/sqrtf(fmaxf(var,0.f)+1e-5f);
  }
  __syncthreads();
  #pragma unroll
  for(int s=0;s<16;s++){
    int elem = tid + 256*s;
    int k = elem & 127, j = elem >> 7;
    float v = (xs[j*132+k] - mean_s[j]) * inv_s[j];
    if(k >= D2C) v *= sinf(dia_w[(size_t)nid[j]*HH+k] + dia_b[(size_t)nid[j]*HH+k]);
    xs[j*132+k] = v;
  }
  __syncthreads();
  int lane = tid & 63, w = tid >> 6;
  int mt = w & 1, ng0 = (w>>1)*4;
  int arow = mt*16 + (lane & 15);
  int koff = (lane >> 4)*8;
  int tb = t*2048;
  ffrag aK[4], aV[4];
  #pragma unroll
  for(int i=0;i<4;i++){ aK[i] = (ffrag){0.f,0.f,0.f,0.f}; aV[i] = (ffrag){0.f,0.f,0.f,0.f}; }
  #pragma unroll
  for(int kc=0;kc<4;kc++){
    const float* ap = xs + arow*132 + kc*32 + koff;
    bfrag a;
    #pragma unroll
    for(int j=0;j<8;j++) a[j] = f2bf(ap[j]);
    #pragma unroll
    for(int nt=0;nt<4;nt++){
      int fi = tb + ((ng0+nt)*4 + kc)*64 + lane;
      bfrag bk = WK[fi];
      bfrag bv = WV[fi];
      aK[nt] = __builtin_amdgcn_mfma_f32_16x16x32_bf16(a, bk, aK[nt], 0, 0, 0);
      aV[nt] = __builtin_amdgcn_mfma_f32_16x16x32_bf16(a, bv, aV[nt], 0, 0, 0);
    }
  }
  int col0 = lane & 15;
  int rb = mt*16 + (lane>>4)*4;
  #pragma unroll
  for(int nt=0;nt<4;nt++){
    int col = (ng0+nt)*16 + col0;
    #pragma unroll
    for(int i=0;i<4;i++){
      int n = rb + i;
      if(n < nn){
        unsigned pk = (unsigned short)f2bf(aK[nt][i]);
        unsigned pv = (unsigned short)f2bf(aV[nt][i]);
        KVp[(size_t)sid[n]*HH + col] = (pv<<16) | pk;
      }
    }
  }
}

// ---- single-matrix projection via MFMA (Q: do_ln=1; O: resid+relu, optional copy).
// xmap: optional row gather for X; rmap: optional row gather for resid.
__global__ void k_gemm_t5(const float* X, const int* xmap, const int* idxb, const int* cnts, int stride,
                          const bfrag* W, const float* resid, const int* rmap, float* Y, float* Y2,
                          int relu, int do_ln){
  int t = blockIdx.y;
  int cnt = cnts[t];
  int base = blockIdx.x * 32;
  if(base >= cnt || cnt == 0) return;
  int nn = min(32, cnt - base);
  const int* ids = idxb + (size_t)t*stride + base;
  __shared__ float xs[32*132];
  __shared__ float red[512];
  __shared__ float mean_s[32], inv_s[32];
  __shared__ int sid[32], xrow[32], rrow[32];
  int tid = threadIdx.x;
  if(tid < 32){
    int s_ = (tid < nn) ? ids[tid] : ids[0];
    sid[tid] = s_;
    xrow[tid] = xmap ? xmap[s_] : s_;
    rrow[tid] = rmap ? rmap[s_] : s_;
  }
  __syncthreads();
  #pragma unroll
  for(int s=0;s<16;s++){
    int elem = tid + 256*s;
    int k = elem & 127, j = elem >> 7;
    xs[j*132 + k] = X[(size_t)xrow[j]*HH + k];
  }
  __syncthreads();
  if(do_ln){
    {
      int j = tid >> 3, p = tid & 7;
      float sm=0.f, sq=0.f;
      const float* xr = xs + j*132 + p*16;
      #pragma unroll
      for(int i=0;i<16;i++){ float v = xr[i]; sm += v; sq += v*v; }
      red[j*8+p] = sm; red[256 + j*8+p] = sq;
    }
    __syncthreads();
    if(tid < 32){
      float sm=0.f, sq=0.f;
      #pragma unroll
      for(int p=0;p<8;p++){ sm += red[tid*8+p]; sq += red[256+tid*8+p]; }
      float mean = sm*(1.f/128.f);
      float var = sq*(1.f/128.f) - mean*mean;
      mean_s[tid] = mean;
      inv_s[tid] = 1.f/sqrtf(fmaxf(var,0.f)+1e-5f);
    }
    __syncthreads();
    #pragma unroll
    for(int s=0;s<16;s++){
      int elem = tid + 256*s;
      int k = elem & 127, j = elem >> 7;
      xs[j*132+k] = (xs[j*132+k] - mean_s[j]) * inv_s[j];
    }
    __syncthreads();
  }
  int lane = tid & 63, w = tid >> 6;
  int mt = w & 1, ng0 = (w>>1)*4;
  int arow = mt*16 + (lane & 15);
  int koff = (lane >> 4)*8;
  int tb = t*2048;
  ffrag acc[4];
  #pragma unroll
  for(int i=0;i<4;i++) acc[i] = (ffrag){0.f,0.f,0.f,0.f};
  #pragma unroll
  for(int kc=0;kc<4;kc++){
    const float* ap = xs + arow*132 + kc*32 + koff;
    bfrag a;
    #pragma unroll
    for(int j=0;j<8;j++) a[j] = f2bf(ap[j]);
    #pragma unroll
    for(int nt=0;nt<4;nt++){
      bfrag b = W[tb + ((ng0+nt)*4 + kc)*64 + lane];
      acc[nt] = __builtin_amdgcn_mfma_f32_16x16x32_bf16(a, b, acc[nt], 0, 0, 0);
    }
  }
  int col0 = lane & 15;
  int rb = mt*16 + (lane>>4)*4;
  #pragma unroll
  for(int nt=0;nt<4;nt++){
    int col = (ng0+nt)*16 + col0;
    #pragma unroll
    for(int i=0;i<4;i++){
      int n = rb + i;
      if(n < nn){
        size_t r = (size_t)sid[n]*HH + col;
        float v = acc[nt][i];
        if(resid){
          v += resid[(size_t)rrow[n]*HH + col];
          if(relu) v = fmaxf(v, 0.f);
        }
        Y[r] = v;
        if(Y2) Y2[r] = v;
      }
    }
  }
}

// EW2all[layer][50][128] = edge_emb @ convE[layer]
__global__ void k_edge_tab4(const float* edge_emb, const float* convE, float* EW2all){
  int r = blockIdx.x; int layer = blockIdx.y; int o = threadIdx.x;
  const float* EWp = convE + (size_t)layer*32*HH;
  float acc = 0.f;
  for(int j=0;j<32;j++) acc += edge_emb[r*32+j]*EWp[j*HH+o];
  EW2all[((size_t)layer*50 + r)*HH + o] = acc;
}

// ---------------- CSR build (per graph) ----------------
__global__ void k_hist_dst(const int* edst, int E, int* cnt){
  int e = blockIdx.x*256 + threadIdx.x;
  if(e < E) atomicAdd(&cnt[edst[e]], 1);
}
__global__ void k_scan(const int* cnt, int n, int* row_ptr, int* cursor){
  __shared__ int tsum[1024];
  int tid = threadIdx.x;
  int per = (n + 1023) / 1024;
  int start = tid*per; int end = min(start+per, n);
  int s = 0;
  for(int i=start;i<end;i++) s += cnt[i];
  tsum[tid] = s; __syncthreads();
  for(int off=1;off<1024;off<<=1){
    int v = (tid>=off) ? tsum[tid-off] : 0;
    __syncthreads();
    tsum[tid] += v;
    __syncthreads();
  }
  int run = (tid==0) ? 0 : tsum[tid-1];
  for(int i=start;i<end;i++){ row_ptr[i]=run; cursor[i]=run; run += cnt[i]; }
  if(end == n) row_ptr[n] = run;
}
__global__ void k_fill_csr(const int* edst, int E, int* cursor, int* eid){
  int e = blockIdx.x*256 + threadIdx.x;
  if(e >= E) return;
  int pos = atomicAdd(&cursor[edst[e]], 1);
  eid[pos] = e;
}
__global__ void k_permute_edges4(const int* eid, const int* esrc, const int* ew, const int* ety,
                                 int E, int4* meta){
  int r = blockIdx.x*256 + threadIdx.x;
  if(r >= E) return;
  int e = eid[r];
  meta[r] = make_int4(esrc[e], ew[e], ety[e], 0);
}

// single-pass attention on packed bf16 KV; 8-edge ILP, packed int4 edge meta,
// 0.25 scale folded into q.
__global__ void k_attn_fused8(const int* __restrict__ row_ptr, const int4* __restrict__ meta,
                              const unsigned* __restrict__ KVp, const float* __restrict__ Qbuf,
                              const float* __restrict__ EW2, const float* __restrict__ mu,
                              float* __restrict__ Abuf){
  int d = blockIdx.x; int o = threadIdx.x;
  int r0 = row_ptr[d], r1 = row_ptr[d+1];
  __shared__ float q[HH];
  q[o] = Qbuf[(size_t)d*HH+o]*0.25f;
  __syncthreads();
  int h = o >> 4;
  float qo = q[o];
  float dn0=0.f, dn1=0.f, dn2=0.f, dn3=0.f;
  float ac0=0.f, ac1=0.f, ac2=0.f, ac3=0.f;
  int r = r0;
  for(; r+7 < r1; r += 8){
    int4 m[8]; unsigned u[8]; float e[8]; float p[8];
    #pragma unroll
    for(int j=0;j<8;j++) m[j] = meta[r+j];
    #pragma unroll
    for(int j=0;j<8;j++) u[j] = KVp[(size_t)m[j].x*HH + o];
    #pragma unroll
    for(int j=0;j<8;j++) e[j] = EW2[m[j].y*HH + o];
    #pragma unroll
    for(int j=0;j<8;j++) p[j] = qo*(__uint_as_float(u[j]<<16) + e[j]);
    #pragma unroll
    for(int j=0;j<8;j++) p[j] += __shfl_xor(p[j], 1, 64);
    #pragma unroll
    for(int j=0;j<8;j++) p[j] += __shfl_xor(p[j], 2, 64);
    #pragma unroll
    for(int j=0;j<8;j++) p[j] += __shfl_xor(p[j], 4, 64);
    #pragma unroll
    for(int j=0;j<8;j++) p[j] += __shfl_xor(p[j], 8, 64);
    float ex[8];
    #pragma unroll
    for(int j=0;j<8;j++) ex[j] = __expf(p[j]*mu[m[j].z*NH+h]);
    dn0 += ex[0]+ex[4]; dn1 += ex[1]+ex[5]; dn2 += ex[2]+ex[6]; dn3 += ex[3]+ex[7];
    ac0 += ex[0]*__uint_as_float(u[0]&0xffff0000u) + ex[4]*__uint_as_float(u[4]&0xffff0000u);
    ac1 += ex[1]*__uint_as_float(u[1]&0xffff0000u) + ex[5]*__uint_as_float(u[5]&0xffff0000u);
    ac2 += ex[2]*__uint_as_float(u[2]&0xffff0000u) + ex[6]*__uint_as_float(u[6]&0xffff0000u);
    ac3 += ex[3]*__uint_as_float(u[3]&0xffff0000u) + ex[7]*__uint_as_float(u[7]&0xffff0000u);
  }
  for(; r+3 < r1; r += 4){
    int4 m[4]; unsigned u[4]; float e[4]; float p[4];
    #pragma unroll
    for(int j=0;j<4;j++) m[j] = meta[r+j];
    #pragma unroll
    for(int j=0;j<4;j++) u[j] = KVp[(size_t)m[j].x*HH + o];
    #pragma unroll
    for(int j=0;j<4;j++) e[j] = EW2[m[j].y*HH + o];
    #pragma unroll
    for(int j=0;j<4;j++) p[j] = qo*(__uint_as_float(u[j]<<16) + e[j]);
    #pragma unroll
    for(int j=0;j<4;j++) p[j] += __shfl_xor(p[j], 1, 64);
    #pragma unroll
    for(int j=0;j<4;j++) p[j] += __shfl_xor(p[j], 2, 64);
    #pragma unroll
    for(int j=0;j<4;j++) p[j] += __shfl_xor(p[j], 4, 64);
    #pragma unroll
    for(int j=0;j<4;j++) p[j] += __shfl_xor(p[j], 8, 64);
    float ex[4];
    #pragma unroll
    for(int j=0;j<4;j++) ex[j] = __expf(p[j]*mu[m[j].z*NH+h]);
    dn0 += ex[0]; dn1 += ex[1]; dn2 += ex[2]; dn3 += ex[3];
    ac0 += ex[0]*__uint_as_float(u[0]&0xffff0000u);
    ac1 += ex[1]*__uint_as_float(u[1]&0xffff0000u);
    ac2 += ex[2]*__uint_as_float(u[2]&0xffff0000u);
    ac3 += ex[3]*__uint_as_float(u[3]&0xffff0000u);
  }
  for(; r < r1; r++){
    int4 m = meta[r];
    unsigned u = KVp[(size_t)m.x*HH + o];
    float p = qo*(__uint_as_float(u<<16) + EW2[m.y*HH + o]);
    p += __shfl_xor(p, 1, 64);
    p += __shfl_xor(p, 2, 64);
    p += __shfl_xor(p, 4, 64);
    p += __shfl_xor(p, 8, 64);
    float ex = __expf(p*mu[m.z*NH+h]);
    dn0 += ex; ac0 += ex*__uint_as_float(u&0xffff0000u);
  }
  float dd = (dn0+dn1)+(dn2+dn3), acc = (ac0+ac1)+(ac2+ac3);
  Abuf[(size_t)d*HH + o] = acc / fmaxf(dd, 1e-9f);
}

// ---------------- stage D: token pooling ----------------
__global__ void k_zero_hist(float* hist2, float* cnt, unsigned* amax, float* aden){
  int i = blockIdx.x*blockDim.x + threadIdx.x;
  if(i < CHILDN*HH) hist2[i] = 0.f;
  if(i < CHILDN){ cnt[i] = 0.f; aden[i] = 0.f; amax[i] = 0x007FFFFFu; }
}

__global__ void k_tokatt(const float* h2f, const int* toknt, const float* ipW, const float* iaW,
                         float* abuf, unsigned* amax, const int* tokid){
  int t = blockIdx.x; int o = threadIdx.x;
  __shared__ float es[HH];
  __shared__ float red[HH];
  int b = t % BB, l = t / BB;
  es[o] = h2f[(b*LL+l)*HH+o];
  __syncthreads();
  int nt = toknt[t];
  const float* w = ipW + (size_t)nt*HH*HH;
  float acc = 0.f;
  for(int j=0;j<HH;j++) acc += es[j]*w[j*HH+o];
  float u = tanhf(acc);
  red[o] = u * iaW[nt*HH+o];
  __syncthreads();
  for(int s=64;s>0;s>>=1){ if(o<s) red[o]+=red[o+s]; __syncthreads(); }
  if(o==0){
    float a = red[0];
    abuf[t] = a;
    atomicMax(&amax[tokid[t]], fenc(a));
  }
}

__global__ void k_tokexp(const int* tokid, float* abuf, const unsigned* amax, float* aden, float* cnt){
  int t = blockIdx.x*blockDim.x + threadIdx.x;
  if(t >= TT) return;
  int c = tokid[t];
  float ex = expf(abuf[t]-fdec(amax[c]));
  abuf[t] = ex;
  atomicAdd(&aden[c], ex);
  atomicAdd(&cnt[c], 1.f);
}

__global__ void k_tokagg(const int* tokid, const float* abuf, const float* aden,
                         const float* h2f, float* hist2){
  int t = blockIdx.x; int o = threadIdx.x;
  int c = tokid[t];
  float w = abuf[t]/fmaxf(aden[c],1e-9f);
  int b = t % BB, l = t / BB;
  atomicAdd(&hist2[c*HH+o], w*h2f[(b*LL+l)*HH+o]);
}

__global__ void k_histfix(const float* cnt, const float* hist_emb, float* hist2){
  int c = blockIdx.x; int o = threadIdx.x;
  if(cnt[c] == 0.f) hist2[c*HH+o] = hist_emb[c*HH+o];
}

// ---------------- parent pooling ----------------
__global__ void k_zero_parent(float* psum, float* pcnt){
  int i = blockIdx.x*blockDim.x + threadIdx.x;
  if(i < PARENTN*HH) psum[i] = 0.f;
  if(i < PARENTN) pcnt[i] = 0.f;
}

__global__ void k_peagg(const int* pe_p, const int* pe_c, const float* cef, float* psum, float* pcnt){
  int i = blockIdx.x; int o = threadIdx.x;
  int p = pe_p[i], c = pe_c[i];
  atomicAdd(&psum[p*HH+o], cef[c*HH+o]);
  if(o==0) atomicAdd(&pcnt[p], 1.f);
}

__global__ void k_parent(const float* psum, const float* pcnt, float* out){
  int i = blockIdx.x; int o = threadIdx.x;
  out[i*HH+o] = psum[i*HH+o]/fmaxf(pcnt[i],1.f);
}

extern "C" void kernel_launch(void* const* d_in, const int* in_sizes, int n_in,
                              void* d_out, int out_size, void* d_ws, size_t ws_size,
                              hipStream_t stream){
  const int* seq     = (const int*)d_in[0];
  const int* seq_nt  = (const int*)d_in[1];
  const int* dur     = (const int*)d_in[2];
  const int* stime   = (const int*)d_in[3];
  const int* etime   = (const int*)d_in[4];
  const int* g1_nid  = (const int*)d_in[5];
  const int* g1_nt   = (const int*)d_in[6];
  const int* g1_esrc = (const int*)d_in[7];
  const int* g1_edst = (const int*)d_in[8];
  const int* g1_ety  = (const int*)d_in[9];
  const int* g1_ew   = (const int*)d_in[10];
  const int* g2_sel  = (const int*)d_in[11];
  const int* g2_esrc = (const int*)d_in[12];
  const int* g2_edst = (const int*)d_in[13];
  const int* g2_ety  = (const int*)d_in[14];
  const int* g2_ew   = (const int*)d_in[15];
  const int* tok_sel = (const int*)d_in[16];
  const int* g4_esrc = (const int*)d_in[17];
  const int* g4_edst = (const int*)d_in[18];
  const int* g4_ety  = (const int*)d_in[19];
  const int* g4_ew   = (const int*)d_in[20];
  const int* pe_p    = (const int*)d_in[21];
  const int* pe_c    = (const int*)d_in[22];
  const float* emb     = (const float*)d_in[23];
  const float* hist_emb= (const float*)d_in[24];
  const float* edge_emb= (const float*)d_in[25];
  const float* dia_w   = (const float*)d_in[26];
  const float* dia_b   = (const float*)d_in[27];
  const float* t2v_w   = (const float*)d_in[28];
  const float* t2v_b   = (const float*)d_in[29];
  const float* exp_W   = (const float*)d_in[30];
  const float* exp_b   = (const float*)d_in[31];
  const float* l1Wi    = (const float*)d_in[32];
  const float* l1Wh    = (const float*)d_in[33];
  const float* l1b     = (const float*)d_in[34];
  const float* l2Wi    = (const float*)d_in[35];
  const float* l2Wh    = (const float*)d_in[36];
  const float* l2b     = (const float*)d_in[37];
  const float* convK   = (const float*)d_in[38];
  const float* convQ   = (const float*)d_in[39];
  const float* convV   = (const float*)d_in[40];
  const float* convO   = (const float*)d_in[41];
  const float* convE   = (const float*)d_in[42];
  const float* convMu  = (const float*)d_in[43];
  const float* ipW     = (const float*)d_in[44];
  const float* iaW     = (const float*)d_in[45];
  const float* skip    = (const float*)d_in[46];
  float* outp = (float*)d_out;

  // workspace arena
  char* wsp = (char*)d_ws;
  size_t off = 0;
  auto A = [&](size_t nbytes)->char*{ char* p = wsp+off; off += (nbytes+255)&~(size_t)255; return p; };
  float*    srcbuf = (float*)   A((size_t)N1SN*HH*4);
  unsigned* KVp    = (unsigned*)A((size_t)N1SN*HH*4);    // packed bf16 [V|K]
  float*    Qbuf   = (float*)   A((size_t)N1DN*HH*4);
  float*    Abuf   = (float*)   A((size_t)N1DN*HH*4);
  float*    xbuf   = (float*)   A((size_t)TT*HH*4);
  float*    gpre   = (float*)   A((size_t)TT*512*4);
  float*    h1     = (float*)   A((size_t)TT*HH*4);
  float*    dst2   = (float*)   A((size_t)TT*HH*4);
  float*    xg     = (float*)   A((size_t)N1DN*HH*4);
  float*    x2     = (float*)   A((size_t)TT*HH*4);
  float*    h2f    = (float*)   A((size_t)TT*HH*4);
  float*    hist2  = (float*)   A((size_t)CHILDN*HH*4);
  float*    cnt    = (float*)   A((size_t)CHILDN*4);
  float*    abuf   = (float*)   A((size_t)TT*4);
  unsigned* amax   = (unsigned*)A((size_t)CHILDN*4);
  float*    aden   = (float*)   A((size_t)CHILDN*4);
  float*    x3     = (float*)   A((size_t)N1DN*HH*4);
  float*    cef    = (float*)   A((size_t)N4DN*HH*4);
  float*    psum   = (float*)   A((size_t)PARENTN*HH*4);
  float*    pcnt   = (float*)   A((size_t)PARENTN*4);
  int*      tokid  = (int*)     A((size_t)TT*4);
  int*      toknt  = (int*)     A((size_t)TT*4);
  int*      gnid2  = (int*)     A((size_t)N2N*4);
  int*      tsrc2  = (int*)     A((size_t)N2N*4);
  int*      idxS1  = (int*)     A((size_t)NTY*N1SN*4);
  int*      idxS2  = (int*)     A((size_t)NTY*N1DN*4);
  int*      idxS3  = (int*)     A((size_t)NTY*N2N*4);
  int*      idxS4  = (int*)     A((size_t)NTY*TT*4);
  int*      idxS5  = (int*)     A((size_t)NTY*N4DN*4);
  int*      cntall = (int*)     A((size_t)5*NTY*4);
  float*    EW2all = (float*)   A((size_t)4*50*HH*4);
  short*    Wsw    = (short*)   A((size_t)64*16384*2);   // bf16-swizzled weights
  int*      g1row  = (int*)     A((size_t)(N1DN+1)*4);
  int*      g1eid  = (int*)     A((size_t)E1N*4);
  int4*     g1meta = (int4*)    A((size_t)E1N*16);
  int*      g2row  = (int*)     A((size_t)(TT+1)*4);
  int*      g2eid  = (int*)     A((size_t)E2N*4);
  int4*     g2meta = (int4*)    A((size_t)E2N*16);
  int*      g4row  = (int*)     A((size_t)(N4DN+1)*4);
  int*      g4eid  = (int*)     A((size_t)E4N*4);
  int4*     g4meta = (int4*)    A((size_t)E4N*16);
  int*      icnt   = (int*)     A((size_t)(N1DN+1)*4);
  int*      icur   = (int*)     A((size_t)(N1DN+1)*4);
  if(off > ws_size) return;  // insufficient scratch: output stays zero

  auto build_csr = [&](const int* edst, const int* esrc, const int* ew, const int* ety,
                       int E, int ndst, int* rowp, int* eid, int4* meta){
    k_zero_intk<<<(ndst+255)/256, 256, 0, stream>>>(icnt, ndst);
    k_hist_dst<<<(E+255)/256, 256, 0, stream>>>(edst, E, icnt);
    k_scan<<<1, 1024, 0, stream>>>(icnt, ndst, rowp, icur);
    k_fill_csr<<<(E+255)/256, 256, 0, stream>>>(edst, E, icur, eid);
    k_permute_edges4<<<(E+255)/256, 256, 0, stream>>>(eid, esrc, ew, ety, E, meta);
  };

  auto run_conv = [&](const float* src_X, const int* src_nid, const int* srcmap, int nsrc,
                      const int* idx_src, int* cnt_src, int stride_src,
                      const float* q_X, const int* q_map,
                      const float* resid_X, const int* r_map, int ndst,
                      const int* idx_dst, int* cnt_dst, int stride_dst,
                      const int* rowp, const int4* meta,
                      int layer, float* outbuf, float* out2, int relu){
    const bfrag* WB = (const bfrag*)Wsw;
    const bfrag* WK = WB + (size_t)( 0 + layer*4)*2048;
    const bfrag* WV = WB + (size_t)(16 + layer*4)*2048;
    const bfrag* WQ = WB + (size_t)(32 + layer*4)*2048;
    const bfrag* WO = WB + (size_t)(48 + layer*4)*2048;
    const float* MU  = convMu + (size_t)layer*NRL*NH;
    const float* EW2 = EW2all + (size_t)layer*50*HH;
    dim3 gkv((nsrc+31)/32, NTY);
    k_gemm_kv5<<<gkv, 256, 0, stream>>>(src_X, src_nid, srcmap, dia_w, dia_b,
                                        idx_src, cnt_src, stride_src, WK, WV, KVp);
    dim3 gq((ndst+31)/32, NTY);
    k_gemm_t5<<<gq, 256, 0, stream>>>(q_X, q_map, idx_dst, cnt_dst, stride_dst, WQ,
                                      (const float*)nullptr, (const int*)nullptr,
                                      Qbuf, (float*)nullptr, 0, 1);
    k_attn_fused8<<<ndst, HH, 0, stream>>>(rowp, meta, KVp, Qbuf, EW2, MU, Abuf);
    k_gemm_t5<<<gq, 256, 0, stream>>>(Abuf, (const int*)nullptr, idx_dst, cnt_dst, stride_dst, WO,
                                      resid_X, r_map, outbuf, out2, relu, 0);
  };

  // ---- stage A: features + LSTM1 (fused scan) ----
  k_featx2<<<TT/32, 512, 0, stream>>>(seq, dur, stime, etime, emb, dia_w, dia_b, t2v_w, t2v_b, exp_W, exp_b, xbuf);
  k_xwi2<<<(TT+15)/16, 256, 0, stream>>>(xbuf, l1Wi, l1b, gpre, TT, 0);
  k_lstm_fused<<<BB, 512, 0, stream>>>(gpre, l1Wh, h1, (float*)nullptr);
  k_tok<<<(TT+255)/256, 256, 0, stream>>>(seq, seq_nt, tokid, toknt);

  // ---- upfront: weight prepack, edge tables, type scatters, g1 CSR ----
  k_prepack<<<64, 256, 0, stream>>>(convK, convV, convQ, convO, Wsw);
  k_edge_tab4<<<dim3(50,4), HH, 0, stream>>>(edge_emb, convE, EW2all);
  k_zero_intk<<<1, 64, 0, stream>>>(cntall, 5*NTY);
  k_scatter_type<<<(N1SN+255)/256, 256, 0, stream>>>(g1_nt, N1SN, cntall+0*NTY, idxS1);
  k_scatter_type<<<(N1DN+255)/256, 256, 0, stream>>>(g1_nt, N1DN, cntall+1*NTY, idxS2);
  k_scatter_type<<<(TT+255)/256, 256, 0, stream>>>(toknt, TT, cntall+3*NTY, idxS4);
  k_scatter_type<<<(N4DN+255)/256, 256, 0, stream>>>(g1_nt, N4DN, cntall+4*NTY, idxS5);
  build_csr(g1_edst, g1_esrc, g1_ew, g1_ety, E1N, N1DN, g1row, g1eid, g1meta);

  // ---- conv1 on g1 (src/dst features gathered from emb via g1_nid in the gemms) ----
  run_conv(emb, g1_nid, g1_nid, N1SN, idxS1, cntall+0*NTY, N1SN,
           emb, g1_nid,
           emb, g1_nid, N1DN, idxS2, cntall+1*NTY, N1DN,
           g1row, g1meta, 0, xg, (float*)nullptr, 1);

  // ---- conv2 on g2 (src features gathered from xg via g2_sel in the gemm) ----
  build_csr(g2_edst, g2_esrc, g2_ew, g2_ety, E2N, TT, g2row, g2eid, g2meta);
  k_prep2i<<<(N2N+255)/256, 256, 0, stream>>>(g2_sel, g1_nid, g1_nt, gnid2, tsrc2);
  k_scatter_type<<<(N2N+255)/256, 256, 0, stream>>>(tsrc2, N2N, cntall+2*NTY, idxS3);
  k_dst2<<<TT, HH, 0, stream>>>(tok_sel, xg, h1, dst2);
  run_conv(xg, gnid2, g2_sel, N2N, idxS3, cntall+2*NTY, N2N,
           dst2, (const int*)nullptr,
           dst2, (const int*)nullptr, TT, idxS4, cntall+3*NTY, TT,
           g2row, g2meta, 1, x2, (float*)nullptr, 1);

  // ---- LSTM2 (h2 is output 0); x2 read directly with permuted layout ----
  k_xwi2<<<(TT+15)/16, 256, 0, stream>>>(x2, l2Wi, l2b, gpre, TT, 1);
  k_lstm_fused<<<BB, 512, 0, stream>>>(gpre, l2Wh, h2f, outp);

  // ---- stage D: token attention pooling -> hist2 ----
  k_zero_hist<<<(CHILDN*HH+255)/256, 256, 0, stream>>>(hist2, cnt, amax, aden);
  k_tokatt<<<TT, HH, 0, stream>>>(h2f, toknt, ipW, iaW, abuf, amax, tokid);
  k_tokexp<<<(TT+255)/256, 256, 0, stream>>>(tokid, abuf, amax, aden, cnt);
  k_tokagg<<<TT, HH, 0, stream>>>(tokid, abuf, aden, h2f, hist2);
  k_histfix<<<CHILDN, HH, 0, stream>>>(cnt, hist_emb, hist2);

  // ---- conv3 on g1 with skip-mixed input (g1 CSR + scatters reused) ----
  k_x0<<<N1SN, HH, 0, stream>>>(g1_nid, g1_nt, emb, hist2, skip, srcbuf);
  run_conv(srcbuf, g1_nid, (const int*)nullptr, N1SN, idxS1, cntall+0*NTY, N1SN,
           srcbuf, (const int*)nullptr,
           srcbuf, (const int*)nullptr, N1DN, idxS2, cntall+1*NTY, N1DN,
           g1row, g1meta, 2, x3, (float*)nullptr, 1);

  // ---- conv4 on g4 (child_embed = output 1, no relu) ----
  build_csr(g4_edst, g4_esrc, g4_ew, g4_ety, E4N, N4DN, g4row, g4eid, g4meta);
  run_conv(x3, g1_nid, (const int*)nullptr, N1DN, idxS2, cntall+1*NTY, N1DN,
           x3, (const int*)nullptr,
           x3, (const int*)nullptr, N4DN, idxS5, cntall+4*NTY, N4DN,
           g4row, g4meta, 3, cef, outp + (size_t)TT*HH, 0);

  // ---- parent pooling (output 2) ----
  k_zero_parent<<<(PARENTN*HH+255)/256, 256, 0, stream>>>(psum, pcnt);
  k_peagg<<<EC2PN, HH, 0, stream>>>(pe_p, pe_c, cef, psum, pcnt);
  k_parent<<<PARENTN, HH, 0, stream>>>(psum, pcnt, outp + (size_t)TT*HH + (size_t)N4DN*HH);
}

// Round 4
// 777.192 us; speedup vs baseline: 1.3934x; 1.1237x over previous
//
#include <hip/hip_runtime.h>
#include <math.h>

#define BB 256
#define LL 20
#define HH 128
#define NH 8
#define D2C 64
#define NTY 4
#define NRL 4
#define CHILDN 30001
#define PARENTN 500
#define N1SN 50000
#define N1DN 20000
#define E1N 300000
#define N2N 20000
#define E2N 200000
#define TT (BB*LL)
#define N4DN 5000
#define E4N 150000
#define EC2PN 8000

typedef __attribute__((ext_vector_type(8))) short bfrag;   // 8 bf16 in 4 VGPRs
typedef __attribute__((ext_vector_type(4))) float ffrag;   // MFMA accumulator

__device__ __forceinline__ unsigned fenc(float f){ unsigned u=__float_as_uint(f); return (u&0x80000000u)? ~u : (u|0x80000000u); }
__device__ __forceinline__ float fdec(unsigned u){ return (u&0x80000000u)? __uint_as_float(u^0x80000000u) : __uint_as_float(~u); }
__device__ __forceinline__ float sigfast(float x){ return 1.f/(1.f+__expf(-x)); }
__device__ __forceinline__ float tanhfast(float x){ float e = __expf(-2.f*x); return (1.f-e)/(1.f+e); }
__device__ __forceinline__ short f2bf(float f){
  unsigned u = __float_as_uint(f);
  unsigned r = u + 0x7FFFu + ((u>>16)&1u);   // round-to-nearest-even
  return (short)(r>>16);
}

// ---------------- upfront init: all zero/poison buffers in one launch ----------------
__global__ void k_init(float* hist2, float* cnt, unsigned* amax, float* aden,
                       float* psum, float* pcnt, int* cntall,
                       int* icnt1, int* icnt2, int* icnt3){
  int i = blockIdx.x*256 + threadIdx.x;
  if(i < CHILDN*HH) hist2[i] = 0.f;
  if(i < CHILDN){ cnt[i] = 0.f; aden[i] = 0.f; amax[i] = 0x007FFFFFu; }
  if(i < PARENTN*HH) psum[i] = 0.f;
  if(i < PARENTN) pcnt[i] = 0.f;
  if(i < 5*NTY) cntall[i] = 0;
  if(i < N1DN) icnt1[i] = 0;
  if(i < TT)   icnt2[i] = 0;
  if(i < N4DN) icnt3[i] = 0;
}

// sin(dia_w + dia_b) per child node, cols 64..127 — shared by all 4 convs
__global__ void k_sindia(const float* __restrict__ dia_w, const float* __restrict__ dia_b,
                         float* __restrict__ sdia){
  int i = blockIdx.x*256 + threadIdx.x;
  if(i >= CHILDN*64) return;
  int c = i >> 6, k = (i & 63) + 64;
  sdia[i] = __sinf(dia_w[(size_t)c*HH+k] + dia_b[(size_t)c*HH+k]);
}

// ---------------- Stage A: feature expansion (tiled: 32 tokens/block) ----------------
__global__ __launch_bounds__(512) void k_featx2(const int* __restrict__ seq, const int* __restrict__ dur,
                        const int* __restrict__ stime, const int* __restrict__ etime,
                        const float* __restrict__ emb, const float* __restrict__ dia_w, const float* __restrict__ dia_b,
                        const float* __restrict__ t2v_w, const float* __restrict__ t2v_b,
                        const float* __restrict__ exp_W, const float* __restrict__ exp_b, float* __restrict__ xout){
  __shared__ float feat[32*273];           // [st(128) | et(128) | tv(16)] per token, stride 273
  int base = blockIdx.x*32;
  int j = threadIdx.x >> 4;                // token 0..31
  int p = threadIdx.x & 15;                // 16 threads/token, 8 cols each
  int row = base + j;
  int node = seq[row];
  float ts = (float)stime[row], te = (float)etime[row];
  const float* ep = emb + (size_t)node*HH;
  float* fr = feat + j*273;
  int o0 = p*8;
  #pragma unroll
  for(int ii=0; ii<8; ii+=4){
    int o = o0 + ii;
    float4 e = *(const float4*)(ep + o);
    float4 st = e, et = e;
    if(o >= D2C){
      float4 w = *(const float4*)(dia_w + (size_t)node*HH + o);
      float4 b = *(const float4*)(dia_b + (size_t)node*HH + o);
      st.x = e.x*__sinf(w.x*ts+b.x); st.y = e.y*__sinf(w.y*ts+b.y);
      st.z = e.z*__sinf(w.z*ts+b.z); st.w = e.w*__sinf(w.w*ts+b.w);
      et.x = e.x*__sinf(w.x*te+b.x); et.y = e.y*__sinf(w.y*te+b.y);
      et.z = e.z*__sinf(w.z*te+b.z); et.w = e.w*__sinf(w.w*te+b.w);
    }
    fr[o] = st.x; fr[o+1] = st.y; fr[o+2] = st.z; fr[o+3] = st.w;
    fr[128+o] = et.x; fr[128+o+1] = et.y; fr[128+o+2] = et.z; fr[128+o+3] = et.w;
  }
  if(p == 0){
    float td = (float)dur[row];
    #pragma unroll
    for(int i=0;i<16;i++){
      float w = t2v_w[i], b = t2v_b[i];
      fr[256+i] = (i==0) ? (w*td + b) : __sinf(w*td + b);
    }
  }
  __syncthreads();
  // GEMM: 32x272 @ 272x128, each thread: 2 rows x 4 cols
  int oc = (threadIdx.x & 31)*4;
  int jg = threadIdx.x >> 5;               // 0..15
  const float* f0 = feat + (jg*2)*273;
  const float* f1 = feat + (jg*2+1)*273;
  float4 a0 = {0,0,0,0}, a1 = {0,0,0,0};
  for(int k=0;k<272;k++){
    float4 w = *(const float4*)(exp_W + (size_t)k*HH + oc);
    float x0 = f0[k], x1 = f1[k];
    a0.x += x0*w.x; a0.y += x0*w.y; a0.z += x0*w.z; a0.w += x0*w.w;
    a1.x += x1*w.x; a1.y += x1*w.y; a1.z += x1*w.z; a1.w += x1*w.w;
  }
  float4 bv = *(const float4*)(exp_b + oc);
  a0.x = fmaxf(a0.x+bv.x, 0.f); a0.y = fmaxf(a0.y+bv.y, 0.f);
  a0.z = fmaxf(a0.z+bv.z, 0.f); a0.w = fmaxf(a0.w+bv.w, 0.f);
  a1.x = fmaxf(a1.x+bv.x, 0.f); a1.y = fmaxf(a1.y+bv.y, 0.f);
  a1.z = fmaxf(a1.z+bv.z, 0.f); a1.w = fmaxf(a1.w+bv.w, 0.f);
  *(float4*)(xout + (size_t)(base + jg*2  )*HH + oc) = a0;
  *(float4*)(xout + (size_t)(base + jg*2+1)*HH + oc) = a1;
}

// tiled x @ Wi + b -> gpre: 16 rows x 512 cols per block; perm=1 reads x in (l*BB+b) layout
__global__ void k_xwi2(const float* x, const float* Wi, const float* bias, float* gpre, int rows, int perm){
  int base = blockIdx.x*16;
  __shared__ float xs[128*17];
  int tid = threadIdx.x;
  #pragma unroll
  for(int s=0;s<8;s++){
    int elem = tid + 256*s;
    int k = elem & 127, j = elem >> 7;
    int r = base + j;
    int src = r;
    if(perm) src = (r % LL)*BB + (r / LL);
    xs[k*17 + j] = (r < rows) ? x[(size_t)src*HH + k] : 0.f;
  }
  __syncthreads();
  int o4 = (tid & 127)*4;
  int ng = tid >> 7;
  float4 a[8];
  #pragma unroll
  for(int j=0;j<8;j++) a[j]=make_float4(0,0,0,0);
  for(int k=0;k<HH;k++){
    float4 w = *(const float4*)(Wi + (size_t)k*512 + o4);
    const float* xr = xs + k*17 + ng*8;
    #pragma unroll
    for(int j=0;j<8;j++){
      float xv = xr[j];
      a[j].x += xv*w.x; a[j].y += xv*w.y; a[j].z += xv*w.z; a[j].w += xv*w.w;
    }
  }
  float4 bv = *(const float4*)(bias + o4);
  #pragma unroll
  for(int j=0;j<8;j++){
    int r = base + ng*8 + j;
    if(r < rows){
      float4 v = a[j];
      v.x += bv.x; v.y += bv.y; v.z += bv.z; v.w += bv.w;
      *(float4*)(gpre + (size_t)r*512 + o4) = v;
    }
  }
}

// fused 20-step LSTM: one block per batch row, Wh column in registers, gpre
// prefetched into registers, activations spread across all 512 threads.
__global__ __launch_bounds__(512, 2) void k_lstm_fused(const float* __restrict__ gpre,
                                                       const float* __restrict__ Wh,
                                                       float* __restrict__ hout,
                                                       float* __restrict__ hout2){
  int b = blockIdx.x;
  int o = threadIdx.x;
  __shared__ float hs[HH];
  __shared__ float act[512];
  float wr[HH];
  #pragma unroll
  for(int h=0;h<HH;h++) wr[h] = Wh[(size_t)h*512 + o];
  float gv[LL];
  const float* gp = gpre + (size_t)b*LL*512 + o;
  #pragma unroll
  for(int l=0;l<LL;l++) gv[l] = gp[(size_t)l*512];
  if(o < HH) hs[o] = 0.f;
  float cc = 0.f;
  int quad = o >> 7;                        // 0=i, 1=f, 2=g, 3=o
  __syncthreads();
  for(int l=0;l<LL;l++){
    float a0=0.f,a1=0.f,a2=0.f,a3=0.f;
    #pragma unroll
    for(int h=0;h<HH;h+=4){
      float4 hv = *(const float4*)&hs[h];
      a0 += hv.x*wr[h];   a1 += hv.y*wr[h+1];
      a2 += hv.z*wr[h+2]; a3 += hv.w*wr[h+3];
    }
    float g = gv[l] + ((a0+a1)+(a2+a3));
    act[o] = (quad==2) ? tanhfast(g) : sigfast(g);
    __syncthreads();
    if(o < HH){
      cc = act[HH+o]*cc + act[o]*act[2*HH+o];
      float hh = act[3*HH+o]*tanhfast(cc);
      hs[o] = hh;
      size_t bi = ((size_t)b*LL + l)*HH + o;
      hout[bi] = hh;
      if(hout2) hout2[bi] = hh;
    }
    __syncthreads();
  }
}

// ---------------- token prep + type scatter (merged) ----------------
__global__ void k_tokprep(const int* __restrict__ seq, const int* __restrict__ seq_nt,
                          int* __restrict__ tokid, int* __restrict__ toknt,
                          int* __restrict__ cnts, int* __restrict__ idxb){
  __shared__ int h[NTY];
  __shared__ int bs[NTY];
  int i = blockIdx.x*256 + threadIdx.x;
  if(threadIdx.x < NTY) h[threadIdx.x] = 0;
  __syncthreads();
  int nt = 0, r = 0;
  bool act = (i < TT);
  if(act){
    int b = i % BB, l = i / BB;
    tokid[i] = seq[b*LL+l];
    nt = seq_nt[b*LL+l];
    toknt[i] = nt;
    r = atomicAdd(&h[nt], 1);
  }
  __syncthreads();
  if(threadIdx.x < NTY && h[threadIdx.x] > 0)
    bs[threadIdx.x] = atomicAdd(&cnts[threadIdx.x], h[threadIdx.x]);
  __syncthreads();
  if(act) idxb[nt*TT + bs[nt] + r] = i;
}

// conv2 src prep + type scatter (merged)
__global__ void k_prep2scat(const int* __restrict__ sel, const int* __restrict__ g1_nid,
                            const int* __restrict__ g1_nt, int* __restrict__ gnid2,
                            int* __restrict__ cnts, int* __restrict__ idxb){
  __shared__ int h[NTY];
  __shared__ int bs[NTY];
  int i = blockIdx.x*256 + threadIdx.x;
  if(threadIdx.x < NTY) h[threadIdx.x] = 0;
  __syncthreads();
  int nt = 0, r = 0;
  bool act = (i < N2N);
  if(act){
    int s = sel[i];
    gnid2[i] = g1_nid[s];
    nt = g1_nt[s];
    r = atomicAdd(&h[nt], 1);
  }
  __syncthreads();
  if(threadIdx.x < NTY && h[threadIdx.x] > 0)
    bs[threadIdx.x] = atomicAdd(&cnts[threadIdx.x], h[threadIdx.x]);
  __syncthreads();
  if(act) idxb[nt*N2N + bs[nt] + r] = i;
}

__global__ void k_dst2(const int* tok_sel, const float* xg, const float* h1, float* dst2){
  int t = blockIdx.x; int o = threadIdx.x;
  int b = t % BB, l = t / BB;
  dst2[t*HH+o] = xg[tok_sel[t]*HH+o] + h1[(b*LL+l)*HH+o];
}

__global__ void k_x0(const int* nid, const int* ntype, const float* emb, const float* hist2,
                     const float* skip, float* srcbuf){
  int i = blockIdx.x; int o = threadIdx.x;
  float a = sigfast(skip[ntype[i]]);
  int nd = nid[i];
  srcbuf[i*HH+o] = emb[nd*HH+o]*a + hist2[nd*HH+o]*(1.f-a);
}

// 3-way type scatter of g1_nt for prefixes N1SN / N1DN / N4DN in one pass
__global__ void k_scatter3(const int* __restrict__ types,
                           int* cnts1, int* idx1, int* cnts2, int* idx2, int* cnts3, int* idx3){
  __shared__ int h[3][NTY];
  __shared__ int bs[3][NTY];
  int i = blockIdx.x*256 + threadIdx.x;
  if(threadIdx.x < 3*NTY) (&h[0][0])[threadIdx.x] = 0;
  __syncthreads();
  int t = 0, r1 = 0, r2 = 0, r3 = 0;
  bool a1 = (i < N1SN), a2 = (i < N1DN), a3 = (i < N4DN);
  if(a1){
    t = types[i];
    r1 = atomicAdd(&h[0][t], 1);
    if(a2) r2 = atomicAdd(&h[1][t], 1);
    if(a3) r3 = atomicAdd(&h[2][t], 1);
  }
  __syncthreads();
  if(threadIdx.x < NTY){
    int ty = threadIdx.x;
    if(h[0][ty] > 0) bs[0][ty] = atomicAdd(&cnts1[ty], h[0][ty]);
    if(h[1][ty] > 0) bs[1][ty] = atomicAdd(&cnts2[ty], h[1][ty]);
    if(h[2][ty] > 0) bs[2][ty] = atomicAdd(&cnts3[ty], h[2][ty]);
  }
  __syncthreads();
  if(a1) idx1[t*N1SN + bs[0][t] + r1] = i;
  if(a2) idx2[t*N1DN + bs[1][t] + r2] = i;
  if(a3) idx3[t*N4DN + bs[2][t] + r3] = i;
}

// ---- weight prepack: fp32 -> bf16 + MFMA B-fragment swizzle.
__global__ void k_prepack(const float* convK, const float* convV, const float* convQ,
                          const float* convO, short* Wsw){
  int m = blockIdx.x;          // 0..63
  int fam = m >> 4;
  int lt = m & 15;             // layer*4 + type
  const float* src = (fam==0?convK:fam==1?convV:fam==2?convQ:convO) + (size_t)lt*HH*HH;
  short* dst = Wsw + (size_t)m*16384;
  for(int s=0;s<64;s++){
    int i = threadIdx.x + 256*s;
    int j = i & 7, lane = (i>>3)&63, kc = (i>>9)&3, nt = i>>11;
    int k = kc*32 + (lane>>4)*8 + j;
    int n = nt*16 + (lane&15);
    dst[i] = f2bf(src[k*HH+n]);
  }
}

// ---- fused KV (z=0) + Q (z=1) projection via MFMA; 32-row tiles, fused LN,
// precomputed sin table for time-mod. One dispatch -> KV and Q co-scheduled.
__global__ __launch_bounds__(256) void k_gemm_kvq(
    const float* __restrict__ Xs, const int* __restrict__ src_nid, const int* __restrict__ smap,
    const float* __restrict__ sdia,
    const int* __restrict__ idxs, const int* __restrict__ cnts_s, int stride_s,
    const bfrag* __restrict__ WK, const bfrag* __restrict__ WV, unsigned* __restrict__ KVp,
    const float* __restrict__ Xq, const int* __restrict__ qmap,
    const int* __restrict__ idxd, const int* __restrict__ cnts_d, int stride_d,
    const bfrag* __restrict__ WQ, float* __restrict__ Qbuf){
  __shared__ float xs[32*132];
  __shared__ float red[512];
  __shared__ float mean_s[32], inv_s[32];
  __shared__ int sid[32], nid[32], xrow[32];
  int t = blockIdx.y;
  int tid = threadIdx.x;
  int base = blockIdx.x * 32;
  if(blockIdx.z == 0){
    // ================= KV path =================
    int cnt = cnts_s[t];
    if(base >= cnt || cnt == 0) return;
    int nn = min(32, cnt - base);
    const int* ids = idxs + (size_t)t*stride_s + base;
    if(tid < 32){
      int s_ = (tid < nn) ? ids[tid] : ids[0];
      sid[tid] = s_; nid[tid] = src_nid[s_];
      xrow[tid] = smap ? smap[s_] : s_;
    }
    __syncthreads();
    #pragma unroll
    for(int s=0;s<16;s++){
      int elem = tid + 256*s;
      int k = elem & 127, j = elem >> 7;
      xs[j*132 + k] = Xs[(size_t)xrow[j]*HH + k];
    }
    __syncthreads();
    {
      int j = tid >> 3, p = tid & 7;
      float sm=0.f, sq=0.f;
      const float* xr = xs + j*132 + p*16;
      #pragma unroll
      for(int i=0;i<16;i++){ float v = xr[i]; sm += v; sq += v*v; }
      red[j*8+p] = sm; red[256 + j*8+p] = sq;
    }
    __syncthreads();
    if(tid < 32){
      float sm=0.f, sq=0.f;
      #pragma unroll
      for(int p=0;p<8;p++){ sm += red[tid*8+p]; sq += red[256+tid*8+p]; }
      float mean = sm*(1.f/128.f);
      float var = sq*(1.f/128.f) - mean*mean;
      mean_s[tid] = mean;
      inv_s[tid] = 1.f/sqrtf(fmaxf(var,0.f)+1e-5f);
    }
    __syncthreads();
    #pragma unroll
    for(int s=0;s<16;s++){
      int elem = tid + 256*s;
      int k = elem & 127, j = elem >> 7;
      float v = (xs[j*132+k] - mean_s[j]) * inv_s[j];
      if(k >= D2C) v *= sdia[(size_t)nid[j]*64 + (k - D2C)];
      xs[j*132+k] = v;
    }
    __syncthreads();
    int lane = tid & 63, w = tid >> 6;
    int mt = w & 1, ng0 = (w>>1)*4;
    int arow = mt*16 + (lane & 15);
    int koff = (lane >> 4)*8;
    int tb = t*2048;
    ffrag aK[4], aV[4];
    #pragma unroll
    for(int i=0;i<4;i++){ aK[i] = (ffrag){0.f,0.f,0.f,0.f}; aV[i] = (ffrag){0.f,0.f,0.f,0.f}; }
    #pragma unroll
    for(int kc=0;kc<4;kc++){
      const float* ap = xs + arow*132 + kc*32 + koff;
      bfrag a;
      #pragma unroll
      for(int j=0;j<8;j++) a[j] = f2bf(ap[j]);
      #pragma unroll
      for(int nt=0;nt<4;nt++){
        int fi = tb + ((ng0+nt)*4 + kc)*64 + lane;
        bfrag bk = WK[fi];
        bfrag bv = WV[fi];
        aK[nt] = __builtin_amdgcn_mfma_f32_16x16x32_bf16(a, bk, aK[nt], 0, 0, 0);
        aV[nt] = __builtin_amdgcn_mfma_f32_16x16x32_bf16(a, bv, aV[nt], 0, 0, 0);
      }
    }
    int col0 = lane & 15;
    int rb = mt*16 + (lane>>4)*4;
    #pragma unroll
    for(int nt=0;nt<4;nt++){
      int col = (ng0+nt)*16 + col0;
      #pragma unroll
      for(int i=0;i<4;i++){
        int n = rb + i;
        if(n < nn){
          unsigned pk = (unsigned short)f2bf(aK[nt][i]);
          unsigned pv = (unsigned short)f2bf(aV[nt][i]);
          KVp[(size_t)sid[n]*HH + col] = (pv<<16) | pk;
        }
      }
    }
  } else {
    // ================= Q path (LN, no time-mod, no resid) =================
    int cnt = cnts_d[t];
    if(base >= cnt || cnt == 0) return;
    int nn = min(32, cnt - base);
    const int* ids = idxd + (size_t)t*stride_d + base;
    if(tid < 32){
      int s_ = (tid < nn) ? ids[tid] : ids[0];
      sid[tid] = s_;
      xrow[tid] = qmap ? qmap[s_] : s_;
    }
    __syncthreads();
    #pragma unroll
    for(int s=0;s<16;s++){
      int elem = tid + 256*s;
      int k = elem & 127, j = elem >> 7;
      xs[j*132 + k] = Xq[(size_t)xrow[j]*HH + k];
    }
    __syncthreads();
    {
      int j = tid >> 3, p = tid & 7;
      float sm=0.f, sq=0.f;
      const float* xr = xs + j*132 + p*16;
      #pragma unroll
      for(int i=0;i<16;i++){ float v = xr[i]; sm += v; sq += v*v; }
      red[j*8+p] = sm; red[256 + j*8+p] = sq;
    }
    __syncthreads();
    if(tid < 32){
      float sm=0.f, sq=0.f;
      #pragma unroll
      for(int p=0;p<8;p++){ sm += red[tid*8+p]; sq += red[256+tid*8+p]; }
      float mean = sm*(1.f/128.f);
      float var = sq*(1.f/128.f) - mean*mean;
      mean_s[tid] = mean;
      inv_s[tid] = 1.f/sqrtf(fmaxf(var,0.f)+1e-5f);
    }
    __syncthreads();
    #pragma unroll
    for(int s=0;s<16;s++){
      int elem = tid + 256*s;
      int k = elem & 127, j = elem >> 7;
      xs[j*132+k] = (xs[j*132+k] - mean_s[j]) * inv_s[j];
    }
    __syncthreads();
    int lane = tid & 63, w = tid >> 6;
    int mt = w & 1, ng0 = (w>>1)*4;
    int arow = mt*16 + (lane & 15);
    int koff = (lane >> 4)*8;
    int tb = t*2048;
    ffrag acc[4];
    #pragma unroll
    for(int i=0;i<4;i++) acc[i] = (ffrag){0.f,0.f,0.f,0.f};
    #pragma unroll
    for(int kc=0;kc<4;kc++){
      const float* ap = xs + arow*132 + kc*32 + koff;
      bfrag a;
      #pragma unroll
      for(int j=0;j<8;j++) a[j] = f2bf(ap[j]);
      #pragma unroll
      for(int nt=0;nt<4;nt++){
        bfrag b = WQ[tb + ((ng0+nt)*4 + kc)*64 + lane];
        acc[nt] = __builtin_amdgcn_mfma_f32_16x16x32_bf16(a, b, acc[nt], 0, 0, 0);
      }
    }
    int col0 = lane & 15;
    int rb = mt*16 + (lane>>4)*4;
    #pragma unroll
    for(int nt=0;nt<4;nt++){
      int col = (ng0+nt)*16 + col0;
      #pragma unroll
      for(int i=0;i<4;i++){
        int n = rb + i;
        if(n < nn) Qbuf[(size_t)sid[n]*HH + col] = acc[nt][i];
      }
    }
  }
}

// ---- O projection via MFMA (resid+relu, optional copy; xmap/rmap row gathers).
__global__ void k_gemm_t5(const float* X, const int* xmap, const int* idxb, const int* cnts, int stride,
                          const bfrag* W, const float* resid, const int* rmap, float* Y, float* Y2,
                          int relu){
  int t = blockIdx.y;
  int cnt = cnts[t];
  int base = blockIdx.x * 32;
  if(base >= cnt || cnt == 0) return;
  int nn = min(32, cnt - base);
  const int* ids = idxb + (size_t)t*stride + base;
  __shared__ float xs[32*132];
  __shared__ int sid[32], xrow[32], rrow[32];
  int tid = threadIdx.x;
  if(tid < 32){
    int s_ = (tid < nn) ? ids[tid] : ids[0];
    sid[tid] = s_;
    xrow[tid] = xmap ? xmap[s_] : s_;
    rrow[tid] = rmap ? rmap[s_] : s_;
  }
  __syncthreads();
  #pragma unroll
  for(int s=0;s<16;s++){
    int elem = tid + 256*s;
    int k = elem & 127, j = elem >> 7;
    xs[j*132 + k] = X[(size_t)xrow[j]*HH + k];
  }
  __syncthreads();
  int lane = tid & 63, w = tid >> 6;
  int mt = w & 1, ng0 = (w>>1)*4;
  int arow = mt*16 + (lane & 15);
  int koff = (lane >> 4)*8;
  int tb = t*2048;
  ffrag acc[4];
  #pragma unroll
  for(int i=0;i<4;i++) acc[i] = (ffrag){0.f,0.f,0.f,0.f};
  #pragma unroll
  for(int kc=0;kc<4;kc++){
    const float* ap = xs + arow*132 + kc*32 + koff;
    bfrag a;
    #pragma unroll
    for(int j=0;j<8;j++) a[j] = f2bf(ap[j]);
    #pragma unroll
    for(int nt=0;nt<4;nt++){
      bfrag b = W[tb + ((ng0+nt)*4 + kc)*64 + lane];
      acc[nt] = __builtin_amdgcn_mfma_f32_16x16x32_bf16(a, b, acc[nt], 0, 0, 0);
    }
  }
  int col0 = lane & 15;
  int rb = mt*16 + (lane>>4)*4;
  #pragma unroll
  for(int nt=0;nt<4;nt++){
    int col = (ng0+nt)*16 + col0;
    #pragma unroll
    for(int i=0;i<4;i++){
      int n = rb + i;
      if(n < nn){
        size_t r = (size_t)sid[n]*HH + col;
        float v = acc[nt][i];
        if(resid){
          v += resid[(size_t)rrow[n]*HH + col];
          if(relu) v = fmaxf(v, 0.f);
        }
        Y[r] = v;
        if(Y2) Y2[r] = v;
      }
    }
  }
}

// EW2all[layer][50][128] = edge_emb @ convE[layer]
__global__ void k_edge_tab4(const float* edge_emb, const float* convE, float* EW2all){
  int r = blockIdx.x; int layer = blockIdx.y; int o = threadIdx.x;
  const float* EWp = convE + (size_t)layer*32*HH;
  float acc = 0.f;
  for(int j=0;j<32;j++) acc += edge_emb[r*32+j]*EWp[j*HH+o];
  EW2all[((size_t)layer*50 + r)*HH + o] = acc;
}

// ---------------- CSR build (batched over 3 graphs) ----------------
__global__ void k_hist_dst(const int* edst, int E, int* cnt){
  int e = blockIdx.x*256 + threadIdx.x;
  if(e < E) atomicAdd(&cnt[edst[e]], 1);
}
// one block per graph: exclusive scan -> row_ptr + cursor
__global__ void k_scan3(const int* c1, int n1, int* r1, int* u1,
                        const int* c2, int n2, int* r2, int* u2,
                        const int* c3, int n3, int* r3, int* u3){
  __shared__ int tsum[1024];
  const int* cnt; int n; int* row_ptr; int* cursor;
  if(blockIdx.x == 0){ cnt=c1; n=n1; row_ptr=r1; cursor=u1; }
  else if(blockIdx.x == 1){ cnt=c2; n=n2; row_ptr=r2; cursor=u2; }
  else { cnt=c3; n=n3; row_ptr=r3; cursor=u3; }
  int tid = threadIdx.x;
  int per = (n + 1023) / 1024;
  int start = tid*per; int end = min(start+per, n);
  int s = 0;
  for(int i=start;i<end;i++) s += cnt[i];
  tsum[tid] = s; __syncthreads();
  for(int off=1;off<1024;off<<=1){
    int v = (tid>=off) ? tsum[tid-off] : 0;
    __syncthreads();
    tsum[tid] += v;
    __syncthreads();
  }
  int run = (tid==0) ? 0 : tsum[tid-1];
  for(int i=start;i<end;i++){ row_ptr[i]=run; cursor[i]=run; run += cnt[i]; }
  if(end == n) row_ptr[n] = run;
}
// fill + permute merged: meta[pos] = {esrc, ew|ety<<16}
__global__ void k_fillperm(const int* edst, const int* esrc, const int* ew, const int* ety,
                           int E, int* cursor, int2* meta){
  int e = blockIdx.x*256 + threadIdx.x;
  if(e >= E) return;
  int pos = atomicAdd(&cursor[edst[e]], 1);
  meta[pos] = make_int2(esrc[e], ew[e] | (ety[e]<<16));
}

// single-pass attention on packed bf16 KV; 8-edge ILP, packed int2 edge meta,
// 0.25 scale folded into q.
__global__ void k_attn_fused8(const int* __restrict__ row_ptr, const int2* __restrict__ meta,
                              const unsigned* __restrict__ KVp, const float* __restrict__ Qbuf,
                              const float* __restrict__ EW2, const float* __restrict__ mu,
                              float* __restrict__ Abuf){
  int d = blockIdx.x; int o = threadIdx.x;
  int r0 = row_ptr[d], r1 = row_ptr[d+1];
  __shared__ float q[HH];
  q[o] = Qbuf[(size_t)d*HH+o]*0.25f;
  __syncthreads();
  int h = o >> 4;
  float qo = q[o];
  float dn0=0.f, dn1=0.f, dn2=0.f, dn3=0.f;
  float ac0=0.f, ac1=0.f, ac2=0.f, ac3=0.f;
  int r = r0;
  for(; r+7 < r1; r += 8){
    int2 m[8]; unsigned u[8]; float e[8]; float p[8];
    #pragma unroll
    for(int j=0;j<8;j++) m[j] = meta[r+j];
    #pragma unroll
    for(int j=0;j<8;j++) u[j] = KVp[(size_t)m[j].x*HH + o];
    #pragma unroll
    for(int j=0;j<8;j++) e[j] = EW2[(m[j].y & 0xffff)*HH + o];
    #pragma unroll
    for(int j=0;j<8;j++) p[j] = qo*(__uint_as_float(u[j]<<16) + e[j]);
    #pragma unroll
    for(int j=0;j<8;j++) p[j] += __shfl_xor(p[j], 1, 64);
    #pragma unroll
    for(int j=0;j<8;j++) p[j] += __shfl_xor(p[j], 2, 64);
    #pragma unroll
    for(int j=0;j<8;j++) p[j] += __shfl_xor(p[j], 4, 64);
    #pragma unroll
    for(int j=0;j<8;j++) p[j] += __shfl_xor(p[j], 8, 64);
    float ex[8];
    #pragma unroll
    for(int j=0;j<8;j++) ex[j] = __expf(p[j]*mu[(m[j].y>>16)*NH+h]);
    dn0 += ex[0]+ex[4]; dn1 += ex[1]+ex[5]; dn2 += ex[2]+ex[6]; dn3 += ex[3]+ex[7];
    ac0 += ex[0]*__uint_as_float(u[0]&0xffff0000u) + ex[4]*__uint_as_float(u[4]&0xffff0000u);
    ac1 += ex[1]*__uint_as_float(u[1]&0xffff0000u) + ex[5]*__uint_as_float(u[5]&0xffff0000u);
    ac2 += ex[2]*__uint_as_float(u[2]&0xffff0000u) + ex[6]*__uint_as_float(u[6]&0xffff0000u);
    ac3 += ex[3]*__uint_as_float(u[3]&0xffff0000u) + ex[7]*__uint_as_float(u[7]&0xffff0000u);
  }
  for(; r+3 < r1; r += 4){
    int2 m[4]; unsigned u[4]; float e[4]; float p[4];
    #pragma unroll
    for(int j=0;j<4;j++) m[j] = meta[r+j];
    #pragma unroll
    for(int j=0;j<4;j++) u[j] = KVp[(size_t)m[j].x*HH + o];
    #pragma unroll
    for(int j=0;j<4;j++) e[j] = EW2[(m[j].y & 0xffff)*HH + o];
    #pragma unroll
    for(int j=0;j<4;j++) p[j] = qo*(__uint_as_float(u[j]<<16) + e[j]);
    #pragma unroll
    for(int j=0;j<4;j++) p[j] += __shfl_xor(p[j], 1, 64);
    #pragma unroll
    for(int j=0;j<4;j++) p[j] += __shfl_xor(p[j], 2, 64);
    #pragma unroll
    for(int j=0;j<4;j++) p[j] += __shfl_xor(p[j], 4, 64);
    #pragma unroll
    for(int j=0;j<4;j++) p[j] += __shfl_xor(p[j], 8, 64);
    float ex[4];
    #pragma unroll
    for(int j=0;j<4;j++) ex[j] = __expf(p[j]*mu[(m[j].y>>16)*NH+h]);
    dn0 += ex[0]; dn1 += ex[1]; dn2 += ex[2]; dn3 += ex[3];
    ac0 += ex[0]*__uint_as_float(u[0]&0xffff0000u);
    ac1 += ex[1]*__uint_as_float(u[1]&0xffff0000u);
    ac2 += ex[2]*__uint_as_float(u[2]&0xffff0000u);
    ac3 += ex[3]*__uint_as_float(u[3]&0xffff0000u);
  }
  for(; r < r1; r++){
    int2 m = meta[r];
    unsigned u = KVp[(size_t)m.x*HH + o];
    float p = qo*(__uint_as_float(u<<16) + EW2[(m.y & 0xffff)*HH + o]);
    p += __shfl_xor(p, 1, 64);
    p += __shfl_xor(p, 2, 64);
    p += __shfl_xor(p, 4, 64);
    p += __shfl_xor(p, 8, 64);
    float ex = __expf(p*mu[(m.y>>16)*NH+h]);
    dn0 += ex; ac0 += ex*__uint_as_float(u&0xffff0000u);
  }
  float dd = (dn0+dn1)+(dn2+dn3), acc = (ac0+ac1)+(ac2+ac3);
  Abuf[(size_t)d*HH + o] = acc / fmaxf(dd, 1e-9f);
}

// ---------------- stage D: token pooling ----------------
__global__ void k_tokatt(const float* h2f, const int* toknt, const float* ipW, const float* iaW,
                         float* abuf, unsigned* amax, const int* tokid){
  int t = blockIdx.x; int o = threadIdx.x;
  __shared__ float es[HH];
  __shared__ float red[HH];
  int b = t % BB, l = t / BB;
  es[o] = h2f[(b*LL+l)*HH+o];
  __syncthreads();
  int nt = toknt[t];
  const float* w = ipW + (size_t)nt*HH*HH;
  float acc = 0.f;
  for(int j=0;j<HH;j++) acc += es[j]*w[j*HH+o];
  float u = tanhfast(acc);
  red[o] = u * iaW[nt*HH+o];
  __syncthreads();
  for(int s=64;s>0;s>>=1){ if(o<s) red[o]+=red[o+s]; __syncthreads(); }
  if(o==0){
    float a = red[0];
    abuf[t] = a;
    atomicMax(&amax[tokid[t]], fenc(a));
  }
}

__global__ void k_tokexp(const int* tokid, float* abuf, const unsigned* amax, float* aden, float* cnt){
  int t = blockIdx.x*blockDim.x + threadIdx.x;
  if(t >= TT) return;
  int c = tokid[t];
  float ex = __expf(abuf[t]-fdec(amax[c]));
  abuf[t] = ex;
  atomicAdd(&aden[c], ex);
  atomicAdd(&cnt[c], 1.f);
}

__global__ void k_tokagg(const int* tokid, const float* abuf, const float* aden,
                         const float* h2f, float* hist2){
  int t = blockIdx.x; int o = threadIdx.x;
  int c = tokid[t];
  float w = abuf[t]/fmaxf(aden[c],1e-9f);
  int b = t % BB, l = t / BB;
  atomicAdd(&hist2[c*HH+o], w*h2f[(b*LL+l)*HH+o]);
}

__global__ void k_histfix(const float* cnt, const float* hist_emb, float* hist2){
  int c = blockIdx.x; int o = threadIdx.x;
  if(cnt[c] == 0.f) hist2[c*HH+o] = hist_emb[c*HH+o];
}

// ---------------- parent pooling ----------------
__global__ void k_peagg(const int* pe_p, const int* pe_c, const float* cef, float* psum, float* pcnt){
  int i = blockIdx.x; int o = threadIdx.x;
  int p = pe_p[i], c = pe_c[i];
  atomicAdd(&psum[p*HH+o], cef[c*HH+o]);
  if(o==0) atomicAdd(&pcnt[p], 1.f);
}

__global__ void k_parent(const float* psum, const float* pcnt, float* out){
  int i = blockIdx.x; int o = threadIdx.x;
  out[i*HH+o] = psum[i*HH+o]/fmaxf(pcnt[i],1.f);
}

extern "C" void kernel_launch(void* const* d_in, const int* in_sizes, int n_in,
                              void* d_out, int out_size, void* d_ws, size_t ws_size,
                              hipStream_t stream){
  const int* seq     = (const int*)d_in[0];
  const int* seq_nt  = (const int*)d_in[1];
  const int* dur     = (const int*)d_in[2];
  const int* stime   = (const int*)d_in[3];
  const int* etime   = (const int*)d_in[4];
  const int* g1_nid  = (const int*)d_in[5];
  const int* g1_nt   = (const int*)d_in[6];
  const int* g1_esrc = (const int*)d_in[7];
  const int* g1_edst = (const int*)d_in[8];
  const int* g1_ety  = (const int*)d_in[9];
  const int* g1_ew   = (const int*)d_in[10];
  const int* g2_sel  = (const int*)d_in[11];
  const int* g2_esrc = (const int*)d_in[12];
  const int* g2_edst = (const int*)d_in[13];
  const int* g2_ety  = (const int*)d_in[14];
  const int* g2_ew   = (const int*)d_in[15];
  const int* tok_sel = (const int*)d_in[16];
  const int* g4_esrc = (const int*)d_in[17];
  const int* g4_edst = (const int*)d_in[18];
  const int* g4_ety  = (const int*)d_in[19];
  const int* g4_ew   = (const int*)d_in[20];
  const int* pe_p    = (const int*)d_in[21];
  const int* pe_c    = (const int*)d_in[22];
  const float* emb     = (const float*)d_in[23];
  const float* hist_emb= (const float*)d_in[24];
  const float* edge_emb= (const float*)d_in[25];
  const float* dia_w   = (const float*)d_in[26];
  const float* dia_b   = (const float*)d_in[27];
  const float* t2v_w   = (const float*)d_in[28];
  const float* t2v_b   = (const float*)d_in[29];
  const float* exp_W   = (const float*)d_in[30];
  const float* exp_b   = (const float*)d_in[31];
  const float* l1Wi    = (const float*)d_in[32];
  const float* l1Wh    = (const float*)d_in[33];
  const float* l1b     = (const float*)d_in[34];
  const float* l2Wi    = (const float*)d_in[35];
  const float* l2Wh    = (const float*)d_in[36];
  const float* l2b     = (const float*)d_in[37];
  const float* convK   = (const float*)d_in[38];
  const float* convQ   = (const float*)d_in[39];
  const float* convV   = (const float*)d_in[40];
  const float* convO   = (const float*)d_in[41];
  const float* convE   = (const float*)d_in[42];
  const float* convMu  = (const float*)d_in[43];
  const float* ipW     = (const float*)d_in[44];
  const float* iaW     = (const float*)d_in[45];
  const float* skip    = (const float*)d_in[46];
  float* outp = (float*)d_out;

  // workspace arena
  char* wsp = (char*)d_ws;
  size_t off = 0;
  auto A = [&](size_t nbytes)->char*{ char* p = wsp+off; off += (nbytes+255)&~(size_t)255; return p; };
  float*    srcbuf = (float*)   A((size_t)N1SN*HH*4);
  unsigned* KVp    = (unsigned*)A((size_t)N1SN*HH*4);    // packed bf16 [V|K]
  float*    Qbuf   = (float*)   A((size_t)N1DN*HH*4);
  float*    Abuf   = (float*)   A((size_t)N1DN*HH*4);
  float*    xbuf   = (float*)   A((size_t)TT*HH*4);
  float*    gpre   = (float*)   A((size_t)TT*512*4);
  float*    h1     = (float*)   A((size_t)TT*HH*4);
  float*    dst2   = (float*)   A((size_t)TT*HH*4);
  float*    xg     = (float*)   A((size_t)N1DN*HH*4);
  float*    x2     = (float*)   A((size_t)TT*HH*4);
  float*    h2f    = (float*)   A((size_t)TT*HH*4);
  float*    hist2  = (float*)   A((size_t)CHILDN*HH*4);
  float*    cnt    = (float*)   A((size_t)CHILDN*4);
  float*    abuf   = (float*)   A((size_t)TT*4);
  unsigned* amax   = (unsigned*)A((size_t)CHILDN*4);
  float*    aden   = (float*)   A((size_t)CHILDN*4);
  float*    x3     = (float*)   A((size_t)N1DN*HH*4);
  float*    cef    = (float*)   A((size_t)N4DN*HH*4);
  float*    psum   = (float*)   A((size_t)PARENTN*HH*4);
  float*    pcnt   = (float*)   A((size_t)PARENTN*4);
  float*    sdia   = (float*)   A((size_t)CHILDN*64*4);  // sin(dia_w+dia_b) cols 64..127
  int*      tokid  = (int*)     A((size_t)TT*4);
  int*      toknt  = (int*)     A((size_t)TT*4);
  int*      gnid2  = (int*)     A((size_t)N2N*4);
  int*      idxS1  = (int*)     A((size_t)NTY*N1SN*4);
  int*      idxS2  = (int*)     A((size_t)NTY*N1DN*4);
  int*      idxS3  = (int*)     A((size_t)NTY*N2N*4);
  int*      idxS4  = (int*)     A((size_t)NTY*TT*4);
  int*      idxS5  = (int*)     A((size_t)NTY*N4DN*4);
  int*      cntall = (int*)     A((size_t)5*NTY*4);
  float*    EW2all = (float*)   A((size_t)4*50*HH*4);
  short*    Wsw    = (short*)   A((size_t)64*16384*2);   // bf16-swizzled weights
  int*      g1row  = (int*)     A((size_t)(N1DN+1)*4);
  int2*     g1meta = (int2*)    A((size_t)E1N*8);
  int*      g2row  = (int*)     A((size_t)(TT+1)*4);
  int2*     g2meta = (int2*)    A((size_t)E2N*8);
  int*      g4row  = (int*)     A((size_t)(N4DN+1)*4);
  int2*     g4meta = (int2*)    A((size_t)E4N*8);
  int*      icnt1  = (int*)     A((size_t)(N1DN+1)*4);
  int*      icur1  = (int*)     A((size_t)(N1DN+1)*4);
  int*      icnt2  = (int*)     A((size_t)(TT+1)*4);
  int*      icur2  = (int*)     A((size_t)(TT+1)*4);
  int*      icnt3  = (int*)     A((size_t)(N4DN+1)*4);
  int*      icur3  = (int*)     A((size_t)(N4DN+1)*4);
  if(off > ws_size) return;  // insufficient scratch: output stays zero

  auto run_conv = [&](const float* src_X, const int* src_nid, const int* srcmap, int nsrc,
                      const int* idx_src, int* cnt_src, int stride_src,
                      const float* q_X, const int* q_map,
                      const float* resid_X, const int* r_map, int ndst,
                      const int* idx_dst, int* cnt_dst, int stride_dst,
                      const int* rowp, const int2* meta,
                      int layer, float* outbuf, float* out2, int relu){
    const bfrag* WB = (const bfrag*)Wsw;
    const bfrag* WK = WB + (size_t)( 0 + layer*4)*2048;
    const bfrag* WV = WB + (size_t)(16 + layer*4)*2048;
    const bfrag* WQ = WB + (size_t)(32 + layer*4)*2048;
    const bfrag* WO = WB + (size_t)(48 + layer*4)*2048;
    const float* MU  = convMu + (size_t)layer*NRL*NH;
    const float* EW2 = EW2all + (size_t)layer*50*HH;
    int gx = max((nsrc+31)/32, (ndst+31)/32);
    dim3 gkvq(gx, NTY, 2);
    k_gemm_kvq<<<gkvq, 256, 0, stream>>>(src_X, src_nid, srcmap, sdia,
                                         idx_src, cnt_src, stride_src, WK, WV, KVp,
                                         q_X, q_map, idx_dst, cnt_dst, stride_dst, WQ, Qbuf);
    k_attn_fused8<<<ndst, HH, 0, stream>>>(rowp, meta, KVp, Qbuf, EW2, MU, Abuf);
    dim3 gq((ndst+31)/32, NTY);
    k_gemm_t5<<<gq, 256, 0, stream>>>(Abuf, (const int*)nullptr, idx_dst, cnt_dst, stride_dst, WO,
                                      resid_X, r_map, outbuf, out2, relu);
  };

  // ---- upfront: init, sin table, weight prepack, edge tables, scatters, CSR ----
  k_init<<<(CHILDN*HH+255)/256, 256, 0, stream>>>(hist2, cnt, amax, aden, psum, pcnt, cntall,
                                                  icnt1, icnt2, icnt3);
  k_sindia<<<(CHILDN*64+255)/256, 256, 0, stream>>>(dia_w, dia_b, sdia);
  k_prepack<<<64, 256, 0, stream>>>(convK, convV, convQ, convO, Wsw);
  k_edge_tab4<<<dim3(50,4), HH, 0, stream>>>(edge_emb, convE, EW2all);
  k_scatter3<<<(N1SN+255)/256, 256, 0, stream>>>(g1_nt, cntall+0*NTY, idxS1,
                                                 cntall+1*NTY, idxS2, cntall+4*NTY, idxS5);
  k_tokprep<<<(TT+255)/256, 256, 0, stream>>>(seq, seq_nt, tokid, toknt, cntall+3*NTY, idxS4);
  k_prep2scat<<<(N2N+255)/256, 256, 0, stream>>>(g2_sel, g1_nid, g1_nt, gnid2, cntall+2*NTY, idxS3);
  k_hist_dst<<<(E1N+255)/256, 256, 0, stream>>>(g1_edst, E1N, icnt1);
  k_hist_dst<<<(E2N+255)/256, 256, 0, stream>>>(g2_edst, E2N, icnt2);
  k_hist_dst<<<(E4N+255)/256, 256, 0, stream>>>(g4_edst, E4N, icnt3);
  k_scan3<<<3, 1024, 0, stream>>>(icnt1, N1DN, g1row, icur1,
                                  icnt2, TT,   g2row, icur2,
                                  icnt3, N4DN, g4row, icur3);
  k_fillperm<<<(E1N+255)/256, 256, 0, stream>>>(g1_edst, g1_esrc, g1_ew, g1_ety, E1N, icur1, g1meta);
  k_fillperm<<<(E2N+255)/256, 256, 0, stream>>>(g2_edst, g2_esrc, g2_ew, g2_ety, E2N, icur2, g2meta);
  k_fillperm<<<(E4N+255)/256, 256, 0, stream>>>(g4_edst, g4_esrc, g4_ew, g4_ety, E4N, icur3, g4meta);

  // ---- stage A: features + LSTM1 (fused scan) ----
  k_featx2<<<TT/32, 512, 0, stream>>>(seq, dur, stime, etime, emb, dia_w, dia_b, t2v_w, t2v_b, exp_W, exp_b, xbuf);
  k_xwi2<<<(TT+15)/16, 256, 0, stream>>>(xbuf, l1Wi, l1b, gpre, TT, 0);
  k_lstm_fused<<<BB, 512, 0, stream>>>(gpre, l1Wh, h1, (float*)nullptr);

  // ---- conv1 on g1 (src/dst features gathered from emb via g1_nid in the gemms) ----
  run_conv(emb, g1_nid, g1_nid, N1SN, idxS1, cntall+0*NTY, N1SN,
           emb, g1_nid,
           emb, g1_nid, N1DN, idxS2, cntall+1*NTY, N1DN,
           g1row, g1meta, 0, xg, (float*)nullptr, 1);

  // ---- conv2 on g2 (src features gathered from xg via g2_sel in the gemm) ----
  k_dst2<<<TT, HH, 0, stream>>>(tok_sel, xg, h1, dst2);
  run_conv(xg, gnid2, g2_sel, N2N, idxS3, cntall+2*NTY, N2N,
           dst2, (const int*)nullptr,
           dst2, (const int*)nullptr, TT, idxS4, cntall+3*NTY, TT,
           g2row, g2meta, 1, x2, (float*)nullptr, 1);

  // ---- LSTM2 (h2 is output 0); x2 read directly with permuted layout ----
  k_xwi2<<<(TT+15)/16, 256, 0, stream>>>(x2, l2Wi, l2b, gpre, TT, 1);
  k_lstm_fused<<<BB, 512, 0, stream>>>(gpre, l2Wh, h2f, outp);

  // ---- stage D: token attention pooling -> hist2 ----
  k_tokatt<<<TT, HH, 0, stream>>>(h2f, toknt, ipW, iaW, abuf, amax, tokid);
  k_tokexp<<<(TT+255)/256, 256, 0, stream>>>(tokid, abuf, amax, aden, cnt);
  k_tokagg<<<TT, HH, 0, stream>>>(tokid, abuf, aden, h2f, hist2);
  k_histfix<<<CHILDN, HH, 0, stream>>>(cnt, hist_emb, hist2);

  // ---- conv3 on g1 with skip-mixed input (g1 CSR + scatters reused) ----
  k_x0<<<N1SN, HH, 0, stream>>>(g1_nid, g1_nt, emb, hist2, skip, srcbuf);
  run_conv(srcbuf, g1_nid, (const int*)nullptr, N1SN, idxS1, cntall+0*NTY, N1SN,
           srcbuf, (const int*)nullptr,
           srcbuf, (const int*)nullptr, N1DN, idxS2, cntall+1*NTY, N1DN,
           g1row, g1meta, 2, x3, (float*)nullptr, 1);

  // ---- conv4 on g4 (child_embed = output 1, no relu) ----
  run_conv(x3, g1_nid, (const int*)nullptr, N1DN, idxS2, cntall+1*NTY, N1DN,
           x3, (const int*)nullptr,
           x3, (const int*)nullptr, N4DN, idxS5, cntall+4*NTY, N4DN,
           g4row, g4meta, 3, cef, outp + (size_t)TT*HH, 0);

  // ---- parent pooling (output 2) ----
  k_peagg<<<EC2PN, HH, 0, stream>>>(pe_p, pe_c, cef, psum, pcnt);
  k_parent<<<PARENTN, HH, 0, stream>>>(psum, pcnt, outp + (size_t)TT*HH + (size_t)N4DN*HH);
}